// Round 6
// baseline (475.294 us; speedup 1.0000x reference)
//
#include <hip/hip_runtime.h>
#include <hip/hip_bf16.h>

#define HH 32
#define WW 64
#define HWSZ 2048
#define ENC 1024
#define VOCAB 5000

typedef __attribute__((ext_vector_type(8))) short short8;
typedef __attribute__((ext_vector_type(4))) short short4v;
typedef __attribute__((ext_vector_type(4))) float f32x4;

#if defined(__has_builtin)
#if __has_builtin(__builtin_amdgcn_global_load_lds)
#define HAVE_GLD_LDS 1
#endif
#endif

__device__ __forceinline__ float sigm(float x) { return 1.0f / (1.0f + expf(-x)); }

__device__ __forceinline__ unsigned short f2bf(float x) {
    unsigned u = __float_as_uint(x);
    unsigned r = (u + 0x7fff + ((u >> 16) & 1)) >> 16;
    return (unsigned short)r;
}

#ifdef HAVE_GLD_LDS
__device__ __forceinline__ void gld_lds16(const unsigned short* g, unsigned short* l) {
    __builtin_amdgcn_global_load_lds(
        (const __attribute__((address_space(1))) void*)g,
        (__attribute__((address_space(3))) void*)l,
        16, 0, 0);
}
#endif

// split-K-16 helpers: lane l of a 16-lane group covers k = i*64 + l*4 .. +3
template <int NI>
__device__ __forceinline__ float dotk(const float* __restrict__ w,
                                      const float* __restrict__ x, int l) {
    float s = 0.f;
    #pragma unroll
    for (int i = 0; i < NI; ++i) {
        f32x4 wv = *(const f32x4*)(w + i * 64 + l * 4);
        f32x4 xv = *(const f32x4*)(x + i * 64 + l * 4);
        s += wv.x * xv.x + wv.y * xv.y + wv.z * xv.z + wv.w * xv.w;
    }
    return s;
}
__device__ __forceinline__ float red16(float s) {
    s += __shfl_xor(s, 1, 64);
    s += __shfl_xor(s, 2, 64);
    s += __shfl_xor(s, 4, 64);
    s += __shfl_xor(s, 8, 64);
    return s;
}

// ---------------- K0: fused prep: ua->bf16 | wr | attsum | coef | GRU1-a | e=0 --
__global__ __launch_bounds__(256) void k_prep(
    const float* __restrict__ ua_w, unsigned short* __restrict__ ub,
    const float* __restrict__ cw, unsigned short* __restrict__ wr,
    const float* __restrict__ att_in, const float* __restrict__ dec,
    const float* __restrict__ c1w, const float* __restrict__ c1b,
    float* __restrict__ out_attsum,
    const float* __restrict__ wb, const float* __restrict__ g,
    const float* __restrict__ bb, const float* __restrict__ rm,
    const float* __restrict__ rv, float* __restrict__ cs, float* __restrict__ csh,
    const int* __restrict__ input_a, const float* __restrict__ input_hidden,
    const float* __restrict__ emb_w,
    const float* __restrict__ w_ih, const float* __restrict__ w_hh,
    const float* __restrict__ b_ih, const float* __restrict__ b_hh,
    float* __restrict__ gi, float* __restrict__ gh,
    float* __restrict__ e_zero)
{
    int blk = blockIdx.x, t = threadIdx.x;
    if (blk < 1024) {                       // ua_w fp32 -> bf16
        int idx = blk * 256 + t;
        ub[idx] = f2bf(ua_w[idx]);
    } else if (blk < 1280) {                // convtan_w -> w_r[tap][o][ci] bf16
        int idx = (blk - 1024) * 256 + t;   // 65536 = (o,ci)
        const float* p = cw + (size_t)idx * 9;
        #pragma unroll
        for (int k = 0; k < 9; ++k) wr[k * 65536 + idx] = f2bf(p[k]);
    } else if (blk < 1408) {                // att_sum = attention_sum + conv1(dec)
        int idx = (blk - 1280) * 256 + t;   // < 32768
        int b = idx >> 11, hw = idx & 2047;
        int h = hw >> 6, w = hw & 63;
        float s = c1b[0];
        #pragma unroll
        for (int dy = 0; dy < 3; ++dy) {
            int hh = h + dy - 1;
            if ((unsigned)hh < (unsigned)HH) {
                #pragma unroll
                for (int dx = 0; dx < 3; ++dx) {
                    int wi = w + dx - 1;
                    if ((unsigned)wi < (unsigned)WW)
                        s += dec[b * HWSZ + hh * WW + wi] * c1w[dy * 3 + dx];
                }
            }
        }
        out_attsum[idx] = att_in[idx] + s;
    } else if (blk == 1408) {               // BN coef fold
        int c = t;
        float s = g[c] * rsqrtf(rv[c] + 1e-5f);
        cs[c] = s;
        csh[c] = (wb[c] - rm[c]) * s + bb[c];
    } else if (blk < 2177) {                // GRU1 gi/gh split-K (768 blocks)
        int gid = (blk - 1409) * 256 + t;   // 196608 = 768j * 16b * 16l
        int o = gid >> 4, l = gid & 15;
        int j = o >> 4, b = o & 15;
        int ia = input_a[b];
        float si = dotk<4>(w_ih + (size_t)j * 256, emb_w + (size_t)ia * 256, l);
        float sh = dotk<4>(w_hh + (size_t)j * 256, input_hidden + b * 256, l);
        si = red16(si); sh = red16(sh);
        if (l == 0) {
            gi[j * 16 + b] = si + b_ih[j];
            gh[j * 16 + b] = sh + b_hh[j];
        }
    } else {                                // zero e accumulator (128 blocks)
        e_zero[(blk - 2177) * 256 + t] = 0.f;
    }
}

// ---------------- K1b: GRU1 gates + emb passthrough + fc1 -> addc (fused) -------
__global__ __launch_bounds__(256) void k_frontbc(
    const int* __restrict__ input_a, const float* __restrict__ emb_w,
    const float* __restrict__ input_hidden,
    const float* __restrict__ gi, const float* __restrict__ gh,
    const float* __restrict__ fc1_w, const float* __restrict__ fc1_b,
    const float* __restrict__ ua_b, const float* __restrict__ uf_b,
    float* __restrict__ st, float* __restrict__ embv, float* __restrict__ addc)
{
    __shared__ float st_s[256];
    int b = blockIdx.x, i = threadIdx.x;
    float r = sigm(gi[i * 16 + b] + gh[i * 16 + b]);
    float z = sigm(gi[(256 + i) * 16 + b] + gh[(256 + i) * 16 + b]);
    float n = tanhf(gi[(512 + i) * 16 + b] + r * gh[(512 + i) * 16 + b]);
    float h0 = input_hidden[b * 256 + i];
    float v = (1.f - z) * n + z * h0;
    st_s[i] = v;
    st[b * 256 + i] = v;
    embv[b * 256 + i] = emb_w[(size_t)input_a[b] * 256 + i];
    __syncthreads();
    int c = i;
    const float* w = fc1_w + (size_t)c * 256;
    float acc = 0.f;
    for (int k = 0; k < 256; ++k) acc += st_s[k] * w[k];
    addc[b * 256 + c] = acc + fc1_b[c] + ua_b[c] + uf_b[c];
}

// ---------------- K3: et-GEMM via MFMA, N=32/block, grid 64x16 ------------------
// out[c=256][hw=32/block] = ua[c][k=1024] @ enc[k][hw]; NHWC bf16 out.
__global__ __launch_bounds__(256) void k_et(
    const float* __restrict__ enc, const unsigned short* __restrict__ ua_bf,
    const float* __restrict__ addc, const float* __restrict__ uf_w,
    const float* __restrict__ attsum, unsigned short* __restrict__ et)
{
    // As[c=256][64k] bf16, swizzled: slot kq holds k-octet (kq ^ (c&7)).  32 KB
    // Bs[p=32][64k]  bf16, same swizzle on p.                              4 KB
    __shared__ __align__(16) unsigned short As[256 * 64];
    __shared__ __align__(16) unsigned short Bs[32 * 64];
    int t = threadIdx.x;
    int hw0 = blockIdx.x * 32, b = blockIdx.y;
    int wv = t >> 6;
    int l15 = t & 15, quad = (t >> 4) & 3;
    int xb = l15 & 7;
    f32x4 acc[4][2];
    #pragma unroll
    for (int i = 0; i < 4; ++i)
        #pragma unroll
        for (int j = 0; j < 2; ++j) acc[i][j] = (f32x4)0.f;

    // B staging role: pixel p (0..31), k-octet g3 (0..7) within BK=64
    int p = t & 31, g3 = t >> 5;
    const float* encb = enc + (size_t)b * ENC * HWSZ + hw0 + p;

    float pfv[8];
    {   // prologue prefetch for k0 = 0
        const float* ep = encb + (size_t)(g3 * 8) * HWSZ;
        #pragma unroll
        for (int j = 0; j < 8; ++j) pfv[j] = ep[(size_t)j * HWSZ];
    }

    for (int k0 = 0; k0 < ENC; k0 += 64) {
        // convert current B subtile, then immediately issue next prefetch
        short8 bv;
        #pragma unroll
        for (int j = 0; j < 8; ++j) bv[j] = (short)f2bf(pfv[j]);
        if (k0 + 64 < ENC) {
            const float* ep = encb + (size_t)(k0 + 64 + g3 * 8) * HWSZ;
            #pragma unroll
            for (int j = 0; j < 8; ++j) pfv[j] = ep[(size_t)j * HWSZ];
        }
        __syncthreads();   // all waves done reading LDS from previous k-step

        // A-tile: 2048 slots (c=s>>3, kq=s&7); dest linear, source pre-swizzled
        #pragma unroll
        for (int i = 0; i < 8; ++i) {
            int s = t + 256 * i;
            int c = s >> 3, kq = s & 7;
            const unsigned short* src =
                ua_bf + (size_t)c * ENC + k0 + ((kq ^ (c & 7)) << 3);
#ifdef HAVE_GLD_LDS
            gld_lds16(src, As + (size_t)(wv * 64 + 256 * i) * 8);
#else
            *(uint4*)(As + (size_t)s * 8) = *(const uint4*)src;
#endif
        }
        // B-tile: swizzled ds_write_b128
        *(short8*)(Bs + p * 64 + ((g3 ^ (p & 7)) << 3)) = bv;
        __syncthreads();   // drains gld_lds (vmcnt) + ds_write (lgkm)

        #pragma unroll
        for (int kk = 0; kk < 2; ++kk) {
            short8 af[4], bfr[2];
            #pragma unroll
            for (int mt = 0; mt < 4; ++mt) {
                int c = wv * 64 + mt * 16 + l15;
                af[mt] = *(const short8*)(As + c * 64 + (((kk * 4 + quad) ^ xb) << 3));
            }
            #pragma unroll
            for (int nt = 0; nt < 2; ++nt) {
                int n = nt * 16 + l15;
                bfr[nt] = *(const short8*)(Bs + n * 64 + (((kk * 4 + quad) ^ xb) << 3));
            }
            #pragma unroll
            for (int mt = 0; mt < 4; ++mt)
                #pragma unroll
                for (int nt = 0; nt < 2; ++nt)
                    acc[mt][nt] = __builtin_amdgcn_mfma_f32_16x16x32_bf16(
                        af[mt], bfr[nt], acc[mt][nt], 0, 0, 0);
        }
    }
    // epilogue: + addc[c] + attsum[hw]*uf_w[c], store NHWC bf16
    float at[2];
    #pragma unroll
    for (int nt = 0; nt < 2; ++nt) at[nt] = attsum[b * HWSZ + hw0 + nt * 16 + l15];
    #pragma unroll
    for (int mt = 0; mt < 4; ++mt) {
        int cb = wv * 64 + mt * 16 + quad * 4;
        float ad[4], uw[4];
        #pragma unroll
        for (int r = 0; r < 4; ++r) { ad[r] = addc[b * 256 + cb + r]; uw[r] = uf_w[cb + r]; }
        #pragma unroll
        for (int nt = 0; nt < 2; ++nt) {
            ushort4 pk;
            pk.x = f2bf(acc[mt][nt][0] + ad[0] + at[nt] * uw[0]);
            pk.y = f2bf(acc[mt][nt][1] + ad[1] + at[nt] * uw[1]);
            pk.z = f2bf(acc[mt][nt][2] + ad[2] + at[nt] * uw[2]);
            pk.w = f2bf(acc[mt][nt][3] + ad[3] + at[nt] * uw[3]);
            *(ushort4*)(et + (size_t)(b * HWSZ + hw0 + nt * 16 + l15) * 256 + cb) = pk;
        }
    }
}

// ---------------- K4: conv3x3 implicit-GEMM MFMA + BN + tanh + v-dot ------------
// v6: v1's proven 2-barrier reg-staged rhythm + v4's merged-c (mt=4, half bfr
// traffic) + single-buffered LDS (38 KB -> 2 blocks/CU at grid 512) + linear
// 512B rows with granule XOR swizzle g^=(row&7) on write AND read (involution)
// -> all 32 banks uniformly loaded, b128 floor. Rows 0/65 pre-zeroed SAME pad.
// Global loads for next row issue BEFORE the barrier (overlap prev compute).
__global__ __launch_bounds__(256, 2) void k_conv(
    const unsigned short* __restrict__ et, const unsigned short* __restrict__ wr,
    const float* __restrict__ cs, const float* __restrict__ csh,
    const float* __restrict__ v_w, float* __restrict__ e_out)
{
    __shared__ __align__(16) unsigned short Ls[66 * 256]; // 33.8 KB
    __shared__ float red[64][17];                          // 4.4 KB
    int t = threadIdx.x;
    int h = blockIdx.x, b = blockIdx.y;
    int wv = t >> 6, l15 = t & 15, quad = (t >> 4) & 3;
    f32x4 acc[4][4];
    #pragma unroll
    for (int i = 0; i < 4; ++i)
        #pragma unroll
        for (int j = 0; j < 4; ++j) acc[i][j] = (f32x4)0.f;

    // zero SAME-pad rows 0 and 65 once (staging only writes rows 1..64)
    if (t < 64) {
        int rsel = t >> 5, g = t & 31;
        *(short8*)(&Ls[(rsel ? 65 : 0) * 256 + g * 8]) = (short8)0;
    }

    int ibase = (h == 0) ? 1 : 0;
    int ni = (h == 0 || h == HH - 1) ? 2 : 3;
    const unsigned short* etb = et + (size_t)b * HH * WW * 256;

    for (int i = 0; i < ni; ++i) {
        int dy = ibase + i;
        const unsigned short* rowp = etb + (size_t)(h + dy - 1) * WW * 256;
        // issue global loads BEFORE the barrier: overlap other waves' compute
        uint4 sv[8];
        #pragma unroll
        for (int j = 0; j < 8; ++j) {
            int idx = t + 256 * j;            // 2048 slots: px = idx>>5, s = idx&31
            sv[j] = *(const uint4*)(rowp + (idx >> 5) * 256 + (idx & 31) * 8);
        }
        __syncthreads();                       // prev compute done reading Ls
        #pragma unroll
        for (int j = 0; j < 8; ++j) {
            int idx = t + 256 * j;
            int row = (idx >> 5) + 1, s = idx & 31;
            *(uint4*)(&Ls[row * 256 + ((s ^ (row & 7)) << 3)]) = sv[j];
        }
        __syncthreads();                       // staging visible to all waves
        __builtin_amdgcn_s_setprio(1);
        #pragma unroll
        for (int dx = 0; dx < 3; ++dx) {
            const unsigned short* wrt = wr + (size_t)(dy * 3 + dx) * 65536;
            #pragma unroll
            for (int kc = 0; kc < 8; ++kc) {
                short8 af[4], bfr[4];
                #pragma unroll
                for (int mt = 0; mt < 4; ++mt)
                    af[mt] = *(const short8*)(wrt +
                        (size_t)(wv * 64 + mt * 16 + l15) * 256 + kc * 32 + quad * 8);
                int g0 = kc * 4 + quad;
                #pragma unroll
                for (int nt = 0; nt < 4; ++nt) {
                    int row = nt * 16 + l15 + dx;          // 0..65; 0/65 = pad
                    bfr[nt] = *(const short8*)(&Ls[row * 256 + ((g0 ^ (row & 7)) << 3)]);
                }
                #pragma unroll
                for (int mt = 0; mt < 4; ++mt)
                    #pragma unroll
                    for (int nt = 0; nt < 4; ++nt)
                        acc[mt][nt] = __builtin_amdgcn_mfma_f32_16x16x32_bf16(
                            af[mt], bfr[nt], acc[mt][nt], 0, 0, 0);
            }
        }
        __builtin_amdgcn_s_setprio(0);
    }

    // epilogue: y = acc*cs + csh; e = sum tanh(y)*v_w over all 256 c (in-block)
    float p[4] = {0.f, 0.f, 0.f, 0.f};
    #pragma unroll
    for (int mt = 0; mt < 4; ++mt) {
        int cb = wv * 64 + mt * 16 + quad * 4;
        #pragma unroll
        for (int r = 0; r < 4; ++r) {
            float sc = cs[cb + r], sh = csh[cb + r], vwv = v_w[cb + r];
            #pragma unroll
            for (int nt = 0; nt < 4; ++nt) {
                float x = acc[mt][nt][r] * sc + sh;
                p[nt] += tanhf(x) * vwv;
            }
        }
    }
    __syncthreads();
    #pragma unroll
    for (int nt = 0; nt < 4; ++nt) red[nt * 16 + l15][wv * 4 + quad] = p[nt];
    __syncthreads();
    if (t < 64) {
        float s = 0.f;
        #pragma unroll
        for (int i = 0; i < 16; ++i) s += red[t][i];
        e_out[(b * HH + h) * WW + t] = s;      // full 256-c sum: plain store
    }
}

// ---------------- K5+K6 fused: softmax(e)->alpha (LDS) + ct reduction -----------
__global__ __launch_bounds__(256) void k_ctalpha(
    const float* __restrict__ enc, const float* __restrict__ e_acc,
    const float* __restrict__ v_b,
    const int* __restrict__ h_mask, const int* __restrict__ w_mask,
    float* __restrict__ alpha_out, float* __restrict__ ct)
{
    __shared__ float a_s[HWSZ];
    __shared__ float rbuf[4];
    int b = blockIdx.y, cg = blockIdx.x, t = threadIdx.x;
    int hm = h_mask[b], wm = w_mask[b];
    float vb = v_b[0];
    float vals[8];
    float psum = 0.f;
    #pragma unroll
    for (int u = 0; u < 8; ++u) {
        int s = u * 256 + t;
        int h = s >> 6, w = s & 63;
        float e = e_acc[b * HWSZ + s] + vb;
        float ex = (h < hm && w < wm) ? expf(e) : 0.f;
        vals[u] = ex;
        psum += ex;
    }
    for (int off = 1; off < 64; off <<= 1) psum += __shfl_xor(psum, off, 64);
    if ((t & 63) == 0) rbuf[t >> 6] = psum;
    __syncthreads();
    float inv = 1.f / (rbuf[0] + rbuf[1] + rbuf[2] + rbuf[3] + 1e-8f);
    #pragma unroll
    for (int u = 0; u < 8; ++u) {
        int s = u * 256 + t;
        float a = vals[u] * inv;
        a_s[s] = a;
        if (cg == 0) alpha_out[b * HWSZ + s] = a;
    }
    __syncthreads();
    int wave = t >> 6, lane = t & 63;
    int c = cg * 4 + wave;
    const float* ep = enc + ((size_t)(b * ENC + c)) * HWSZ;
    float s = 0.f;
    for (int i = lane; i < HWSZ; i += 64) s += ep[i] * a_s[i];
    for (int off = 32; off; off >>= 1) s += __shfl_down(s, off, 64);
    if (lane == 0) ct[b * ENC + c] = s;
}

// ---------------- K7a: gi/gh for GRU2, split-K-16 (768 blocks) ------------------
__global__ __launch_bounds__(256) void k_gru2a(
    const float* __restrict__ ct, const float* __restrict__ st,
    const float* __restrict__ w_ih, const float* __restrict__ w_hh,
    const float* __restrict__ b_ih, const float* __restrict__ b_hh,
    float* __restrict__ gi, float* __restrict__ gh)
{
    int gid = blockIdx.x * 256 + threadIdx.x;
    int o = gid >> 4, l = gid & 15;
    int j = o >> 4, b = o & 15;
    float si = dotk<16>(w_ih + (size_t)j * ENC, ct + b * ENC, l);
    float sh = dotk<4>(w_hh + (size_t)j * 256, st + b * 256, l);
    si = red16(si); sh = red16(sh);
    if (l == 0) {
        gi[j * 16 + b] = si + b_ih[j];
        gh[j * 16 + b] = sh + b_hh[j];
    }
}

// ---------------- K7b: GRU2 gates -> h2 / hidden_next ---------------------------
__global__ __launch_bounds__(256) void k_gates2(
    const float* __restrict__ st, const float* __restrict__ gi,
    const float* __restrict__ gh, float* __restrict__ h2,
    float* __restrict__ out_hidden)
{
    int b = blockIdx.x, i = threadIdx.x;
    float r = sigm(gi[i * 16 + b] + gh[i * 16 + b]);
    float z = sigm(gi[(256 + i) * 16 + b] + gh[(256 + i) * 16 + b]);
    float n = tanhf(gi[(512 + i) * 16 + b] + r * gh[(512 + i) * 16 + b]);
    float v = (1.f - z) * n + z * st[b * 256 + i];
    h2[b * 256 + i] = v;
    out_hidden[b * 256 + i] = v;
}

// ---------------- K8: pre = h2@fc2^T + emb@emb2^T + ct@wc^T, split-K-16 ---------
__global__ __launch_bounds__(256) void k_pre(
    const float* __restrict__ h2, const float* __restrict__ emb,
    const float* __restrict__ ct,
    const float* __restrict__ fc2_w, const float* __restrict__ fc2_b,
    const float* __restrict__ emb2_w, const float* __restrict__ emb2_b,
    const float* __restrict__ wc_w, const float* __restrict__ wc_b,
    float* __restrict__ pre)
{
    int gid = blockIdx.x * 256 + threadIdx.x;  // 128 blocks: 128j*16b*16l
    int o = gid >> 4, l = gid & 15;
    int j = o >> 4, b = o & 15;
    float s = dotk<4>(fc2_w + (size_t)j * 256, h2 + b * 256, l)
            + dotk<4>(emb2_w + (size_t)j * 256, emb + b * 256, l)
            + dotk<16>(wc_w + (size_t)j * ENC, ct + b * ENC, l);
    s = red16(s);
    if (l == 0) pre[b * 128 + j] = s + fc2_b[j] + emb2_b[j] + wc_b[j];
}

// ---------------- K9: logits = pre @ out_w^T + out_b, split-K-16 ----------------
__global__ __launch_bounds__(256) void k_logits(
    const float* __restrict__ pre, const float* __restrict__ out_w,
    const float* __restrict__ out_b, float* __restrict__ logits)
{
    int gid = blockIdx.x * 256 + threadIdx.x;  // 5000 blocks: 5000j*16b*16l
    int o = gid >> 4, l = gid & 15;
    int j = o >> 4, b = o & 15;
    float s = dotk<2>(out_w + (size_t)j * 128, pre + b * 128, l);
    s = red16(s);
    if (l == 0) logits[b * VOCAB + j] = s + out_b[j];
}

// ---------------- K10: log_softmax ----------------------------------------------
__global__ __launch_bounds__(256) void k_lsm(
    const float* __restrict__ logits, float* __restrict__ out)
{
    __shared__ float buf[VOCAB];
    __shared__ float rbuf[4];
    int b = blockIdx.x, t = threadIdx.x;
    float mx = -1e30f;
    for (int s = t; s < VOCAB; s += 256) {
        float v = logits[b * VOCAB + s];
        buf[s] = v;
        mx = fmaxf(mx, v);
    }
    for (int off = 1; off < 64; off <<= 1) mx = fmaxf(mx, __shfl_xor(mx, off, 64));
    if ((t & 63) == 0) rbuf[t >> 6] = mx;
    __syncthreads();
    mx = fmaxf(fmaxf(rbuf[0], rbuf[1]), fmaxf(rbuf[2], rbuf[3]));
    __syncthreads();
    float se = 0.f;
    for (int s = t; s < VOCAB; s += 256) se += expf(buf[s] - mx);
    for (int off = 1; off < 64; off <<= 1) se += __shfl_xor(se, off, 64);
    if ((t & 63) == 0) rbuf[t >> 6] = se;
    __syncthreads();
    float lse = mx + logf(rbuf[0] + rbuf[1] + rbuf[2] + rbuf[3]);
    for (int s = t; s < VOCAB; s += 256) out[b * VOCAB + s] = buf[s] - lse;
}

extern "C" void kernel_launch(void* const* d_in, const int* in_sizes, int n_in,
                              void* d_out, int out_size, void* d_ws, size_t ws_size,
                              hipStream_t stream)
{
    const int*   input_a      = (const int*)d_in[0];
    const float* input_hidden = (const float*)d_in[1];
    const float* enc          = (const float*)d_in[2];
    const float* att_in       = (const float*)d_in[3];
    const float* dec_att      = (const float*)d_in[4];
    const int*   h_mask       = (const int*)d_in[5];
    const int*   w_mask       = (const int*)d_in[6];
    const float* emb_w        = (const float*)d_in[11];
    const float* g1_wih       = (const float*)d_in[12];
    const float* g1_whh       = (const float*)d_in[13];
    const float* g1_bih       = (const float*)d_in[14];
    const float* g1_bhh       = (const float*)d_in[15];
    const float* fc1_w        = (const float*)d_in[16];
    const float* fc1_b        = (const float*)d_in[17];
    const float* g2_wih       = (const float*)d_in[18];
    const float* g2_whh       = (const float*)d_in[19];
    const float* g2_bih       = (const float*)d_in[20];
    const float* g2_bhh       = (const float*)d_in[21];
    const float* out_w        = (const float*)d_in[22];
    const float* out_b        = (const float*)d_in[23];
    const float* emb2_w       = (const float*)d_in[24];
    const float* emb2_b       = (const float*)d_in[25];
    const float* c1w          = (const float*)d_in[26];
    const float* c1b          = (const float*)d_in[27];
    const float* ctw          = (const float*)d_in[28];
    const float* ctb          = (const float*)d_in[29];
    const float* fc2_w        = (const float*)d_in[30];
    const float* fc2_b        = (const float*)d_in[31];
    const float* ua_w         = (const float*)d_in[32];
    const float* ua_b         = (const float*)d_in[33];
    const float* uf_w         = (const float*)d_in[34];
    const float* uf_b         = (const float*)d_in[35];
    const float* v_w          = (const float*)d_in[36];
    const float* v_b          = (const float*)d_in[37];
    const float* wc_w         = (const float*)d_in[38];
    const float* wc_b         = (const float*)d_in[39];
    const float* bn_g         = (const float*)d_in[40];
    const float* bn_b         = (const float*)d_in[41];
    const float* bn_rm        = (const float*)d_in[42];
    const float* bn_rv        = (const float*)d_in[43];

    // output layout: log_softmax(16x5000) | hidden_next(16x256) | alpha(16x2048) | att_sum(16x2048)
    float* out        = (float*)d_out;
    float* out_logits = out;
    float* out_hidden = out + 80000;
    float* out_alpha  = out + 84096;
    float* out_attsum = out + 116864;

    // workspace layout
    char* ws = (char*)d_ws;
    unsigned short* et_t  = (unsigned short*)ws;                 // 16.78 MB (NHWC bf16)
    unsigned short* ua_bf = (unsigned short*)(ws + 16777216);    // 0.52 MB
    unsigned short* w_r   = (unsigned short*)(ws + 17301504);    // 1.18 MB
    float* f      = (float*)(ws + 18481152);
    float* st     = f;             // 4096
    float* embv   = f + 4096;      // 4096
    float* addc   = f + 8192;      // 4096
    float* e_ws   = f + 12288;     // 32768
    float* ct     = f + 45056;     // 16384
    float* h2     = f + 61440;     // 4096
    float* pre    = f + 65536;     // 2048
    float* logits = f + 67584;     // 80000
    float* gi1    = f + 147584;    // 12288
    float* gh1    = f + 159872;    // 12288
    float* gi2    = f + 172160;    // 12288
    float* gh2    = f + 184448;    // 12288
    float* cs     = f + 196736;    // 256
    float* csh    = f + 196992;    // 256

    k_prep<<<2305, 256, 0, stream>>>(ua_w, ua_bf, ctw, w_r,
                                     att_in, dec_att, c1w, c1b, out_attsum,
                                     ctb, bn_g, bn_b, bn_rm, bn_rv, cs, csh,
                                     input_a, input_hidden, emb_w,
                                     g1_wih, g1_whh, g1_bih, g1_bhh, gi1, gh1,
                                     e_ws);
    k_frontbc<<<16, 256, 0, stream>>>(input_a, emb_w, input_hidden, gi1, gh1,
                                      fc1_w, fc1_b, ua_b, uf_b, st, embv, addc);

    k_et<<<dim3(64, 16), 256, 0, stream>>>(enc, ua_bf, addc, uf_w, out_attsum, et_t);
    k_conv<<<dim3(32, 16), 256, 0, stream>>>(et_t, w_r, cs, csh, v_w, e_ws);

    k_ctalpha<<<dim3(256, 16), 256, 0, stream>>>(enc, e_ws, v_b, h_mask, w_mask,
                                                 out_alpha, ct);
    k_gru2a<<<768, 256, 0, stream>>>(ct, st, g2_wih, g2_whh, g2_bih, g2_bhh, gi2, gh2);
    k_gates2<<<16, 256, 0, stream>>>(st, gi2, gh2, h2, out_hidden);
    k_pre<<<128, 256, 0, stream>>>(h2, embv, ct, fc2_w, fc2_b, emb2_w, emb2_b,
                                   wc_w, wc_b, pre);
    k_logits<<<5000, 256, 0, stream>>>(pre, out_w, out_b, logits);
    k_lsm<<<16, 256, 0, stream>>>(logits, out_logits);
}

// Round 7
// 454.469 us; speedup vs baseline: 1.0458x; 1.0458x over previous
//
#include <hip/hip_runtime.h>
#include <hip/hip_bf16.h>

#define HH 32
#define WW 64
#define HWSZ 2048
#define ENC 1024
#define VOCAB 5000

typedef __attribute__((ext_vector_type(8))) short short8;
typedef __attribute__((ext_vector_type(4))) short short4v;
typedef __attribute__((ext_vector_type(4))) float f32x4;

#if defined(__has_builtin)
#if __has_builtin(__builtin_amdgcn_global_load_lds)
#define HAVE_GLD_LDS 1
#endif
#endif

__device__ __forceinline__ float sigm(float x) { return 1.0f / (1.0f + expf(-x)); }

__device__ __forceinline__ unsigned short f2bf(float x) {
    unsigned u = __float_as_uint(x);
    unsigned r = (u + 0x7fff + ((u >> 16) & 1)) >> 16;
    return (unsigned short)r;
}

#ifdef HAVE_GLD_LDS
__device__ __forceinline__ void gld_lds16(const unsigned short* g, unsigned short* l) {
    __builtin_amdgcn_global_load_lds(
        (const __attribute__((address_space(1))) void*)g,
        (__attribute__((address_space(3))) void*)l,
        16, 0, 0);
}
#endif

// split-K-16 helpers: lane l of a 16-lane group covers k = i*64 + l*4 .. +3
template <int NI>
__device__ __forceinline__ float dotk(const float* __restrict__ w,
                                      const float* __restrict__ x, int l) {
    float s = 0.f;
    #pragma unroll
    for (int i = 0; i < NI; ++i) {
        f32x4 wv = *(const f32x4*)(w + i * 64 + l * 4);
        f32x4 xv = *(const f32x4*)(x + i * 64 + l * 4);
        s += wv.x * xv.x + wv.y * xv.y + wv.z * xv.z + wv.w * xv.w;
    }
    return s;
}
__device__ __forceinline__ float red16(float s) {
    s += __shfl_xor(s, 1, 64);
    s += __shfl_xor(s, 2, 64);
    s += __shfl_xor(s, 4, 64);
    s += __shfl_xor(s, 8, 64);
    return s;
}

// ---------------- K0: fused prep: ua->bf16 | wr | attsum | coef | GRU1-a | e=0 --
__global__ __launch_bounds__(256) void k_prep(
    const float* __restrict__ ua_w, unsigned short* __restrict__ ub,
    const float* __restrict__ cw, unsigned short* __restrict__ wr,
    const float* __restrict__ att_in, const float* __restrict__ dec,
    const float* __restrict__ c1w, const float* __restrict__ c1b,
    float* __restrict__ out_attsum,
    const float* __restrict__ wb, const float* __restrict__ g,
    const float* __restrict__ bb, const float* __restrict__ rm,
    const float* __restrict__ rv, float* __restrict__ cs, float* __restrict__ csh,
    const int* __restrict__ input_a, const float* __restrict__ input_hidden,
    const float* __restrict__ emb_w,
    const float* __restrict__ w_ih, const float* __restrict__ w_hh,
    const float* __restrict__ b_ih, const float* __restrict__ b_hh,
    float* __restrict__ gi, float* __restrict__ gh,
    float* __restrict__ e_zero)
{
    int blk = blockIdx.x, t = threadIdx.x;
    if (blk < 1024) {                       // ua_w fp32 -> bf16
        int idx = blk * 256 + t;
        ub[idx] = f2bf(ua_w[idx]);
    } else if (blk < 1280) {                // convtan_w -> w_r[tap][o][ci] bf16
        int idx = (blk - 1024) * 256 + t;   // 65536 = (o,ci)
        const float* p = cw + (size_t)idx * 9;
        #pragma unroll
        for (int k = 0; k < 9; ++k) wr[k * 65536 + idx] = f2bf(p[k]);
    } else if (blk < 1408) {                // att_sum = attention_sum + conv1(dec)
        int idx = (blk - 1280) * 256 + t;   // < 32768
        int b = idx >> 11, hw = idx & 2047;
        int h = hw >> 6, w = hw & 63;
        float s = c1b[0];
        #pragma unroll
        for (int dy = 0; dy < 3; ++dy) {
            int hh = h + dy - 1;
            if ((unsigned)hh < (unsigned)HH) {
                #pragma unroll
                for (int dx = 0; dx < 3; ++dx) {
                    int wi = w + dx - 1;
                    if ((unsigned)wi < (unsigned)WW)
                        s += dec[b * HWSZ + hh * WW + wi] * c1w[dy * 3 + dx];
                }
            }
        }
        out_attsum[idx] = att_in[idx] + s;
    } else if (blk == 1408) {               // BN coef fold
        int c = t;
        float s = g[c] * rsqrtf(rv[c] + 1e-5f);
        cs[c] = s;
        csh[c] = (wb[c] - rm[c]) * s + bb[c];
    } else if (blk < 2177) {                // GRU1 gi/gh split-K (768 blocks)
        int gid = (blk - 1409) * 256 + t;   // 196608 = 768j * 16b * 16l
        int o = gid >> 4, l = gid & 15;
        int j = o >> 4, b = o & 15;
        int ia = input_a[b];
        float si = dotk<4>(w_ih + (size_t)j * 256, emb_w + (size_t)ia * 256, l);
        float sh = dotk<4>(w_hh + (size_t)j * 256, input_hidden + b * 256, l);
        si = red16(si); sh = red16(sh);
        if (l == 0) {
            gi[j * 16 + b] = si + b_ih[j];
            gh[j * 16 + b] = sh + b_hh[j];
        }
    } else {                                // zero e accumulator (128 blocks)
        e_zero[(blk - 2177) * 256 + t] = 0.f;
    }
}

// ---------------- K1b: GRU1 gates + emb passthrough + fc1 -> addc (fused) -------
__global__ __launch_bounds__(256) void k_frontbc(
    const int* __restrict__ input_a, const float* __restrict__ emb_w,
    const float* __restrict__ input_hidden,
    const float* __restrict__ gi, const float* __restrict__ gh,
    const float* __restrict__ fc1_w, const float* __restrict__ fc1_b,
    const float* __restrict__ ua_b, const float* __restrict__ uf_b,
    float* __restrict__ st, float* __restrict__ embv, float* __restrict__ addc)
{
    __shared__ float st_s[256];
    int b = blockIdx.x, i = threadIdx.x;
    float r = sigm(gi[i * 16 + b] + gh[i * 16 + b]);
    float z = sigm(gi[(256 + i) * 16 + b] + gh[(256 + i) * 16 + b]);
    float n = tanhf(gi[(512 + i) * 16 + b] + r * gh[(512 + i) * 16 + b]);
    float h0 = input_hidden[b * 256 + i];
    float v = (1.f - z) * n + z * h0;
    st_s[i] = v;
    st[b * 256 + i] = v;
    embv[b * 256 + i] = emb_w[(size_t)input_a[b] * 256 + i];
    __syncthreads();
    int c = i;
    const float* w = fc1_w + (size_t)c * 256;
    float acc = 0.f;
    for (int k = 0; k < 256; ++k) acc += st_s[k] * w[k];
    addc[b * 256 + c] = acc + fc1_b[c] + ua_b[c] + uf_b[c];
}

// ---------------- K3: et-GEMM via MFMA, N=32/block, grid 64x16 ------------------
// out[c=256][hw=32/block] = ua[c][k=1024] @ enc[k][hw]; NHWC bf16 out.
__global__ __launch_bounds__(256) void k_et(
    const float* __restrict__ enc, const unsigned short* __restrict__ ua_bf,
    const float* __restrict__ addc, const float* __restrict__ uf_w,
    const float* __restrict__ attsum, unsigned short* __restrict__ et)
{
    // As[c=256][64k] bf16, swizzled: slot kq holds k-octet (kq ^ (c&7)).  32 KB
    // Bs[p=32][64k]  bf16, same swizzle on p.                              4 KB
    __shared__ __align__(16) unsigned short As[256 * 64];
    __shared__ __align__(16) unsigned short Bs[32 * 64];
    int t = threadIdx.x;
    int hw0 = blockIdx.x * 32, b = blockIdx.y;
    int wv = t >> 6;
    int l15 = t & 15, quad = (t >> 4) & 3;
    int xb = l15 & 7;
    f32x4 acc[4][2];
    #pragma unroll
    for (int i = 0; i < 4; ++i)
        #pragma unroll
        for (int j = 0; j < 2; ++j) acc[i][j] = (f32x4)0.f;

    // B staging role: pixel p (0..31), k-octet g3 (0..7) within BK=64
    int p = t & 31, g3 = t >> 5;
    const float* encb = enc + (size_t)b * ENC * HWSZ + hw0 + p;

    float pfv[8];
    {   // prologue prefetch for k0 = 0
        const float* ep = encb + (size_t)(g3 * 8) * HWSZ;
        #pragma unroll
        for (int j = 0; j < 8; ++j) pfv[j] = ep[(size_t)j * HWSZ];
    }

    for (int k0 = 0; k0 < ENC; k0 += 64) {
        // convert current B subtile, then immediately issue next prefetch
        short8 bv;
        #pragma unroll
        for (int j = 0; j < 8; ++j) bv[j] = (short)f2bf(pfv[j]);
        if (k0 + 64 < ENC) {
            const float* ep = encb + (size_t)(k0 + 64 + g3 * 8) * HWSZ;
            #pragma unroll
            for (int j = 0; j < 8; ++j) pfv[j] = ep[(size_t)j * HWSZ];
        }
        __syncthreads();   // all waves done reading LDS from previous k-step

        // A-tile: 2048 slots (c=s>>3, kq=s&7); dest linear, source pre-swizzled
        #pragma unroll
        for (int i = 0; i < 8; ++i) {
            int s = t + 256 * i;
            int c = s >> 3, kq = s & 7;
            const unsigned short* src =
                ua_bf + (size_t)c * ENC + k0 + ((kq ^ (c & 7)) << 3);
#ifdef HAVE_GLD_LDS
            gld_lds16(src, As + (size_t)(wv * 64 + 256 * i) * 8);
#else
            *(uint4*)(As + (size_t)s * 8) = *(const uint4*)src;
#endif
        }
        // B-tile: swizzled ds_write_b128
        *(short8*)(Bs + p * 64 + ((g3 ^ (p & 7)) << 3)) = bv;
        __syncthreads();   // drains gld_lds (vmcnt) + ds_write (lgkm)

        #pragma unroll
        for (int kk = 0; kk < 2; ++kk) {
            short8 af[4], bfr[2];
            #pragma unroll
            for (int mt = 0; mt < 4; ++mt) {
                int c = wv * 64 + mt * 16 + l15;
                af[mt] = *(const short8*)(As + c * 64 + (((kk * 4 + quad) ^ xb) << 3));
            }
            #pragma unroll
            for (int nt = 0; nt < 2; ++nt) {
                int n = nt * 16 + l15;
                bfr[nt] = *(const short8*)(Bs + n * 64 + (((kk * 4 + quad) ^ xb) << 3));
            }
            #pragma unroll
            for (int mt = 0; mt < 4; ++mt)
                #pragma unroll
                for (int nt = 0; nt < 2; ++nt)
                    acc[mt][nt] = __builtin_amdgcn_mfma_f32_16x16x32_bf16(
                        af[mt], bfr[nt], acc[mt][nt], 0, 0, 0);
        }
    }
    // epilogue: + addc[c] + attsum[hw]*uf_w[c], store NHWC bf16
    float at[2];
    #pragma unroll
    for (int nt = 0; nt < 2; ++nt) at[nt] = attsum[b * HWSZ + hw0 + nt * 16 + l15];
    #pragma unroll
    for (int mt = 0; mt < 4; ++mt) {
        int cb = wv * 64 + mt * 16 + quad * 4;
        float ad[4], uw[4];
        #pragma unroll
        for (int r = 0; r < 4; ++r) { ad[r] = addc[b * 256 + cb + r]; uw[r] = uf_w[cb + r]; }
        #pragma unroll
        for (int nt = 0; nt < 2; ++nt) {
            ushort4 pk;
            pk.x = f2bf(acc[mt][nt][0] + ad[0] + at[nt] * uw[0]);
            pk.y = f2bf(acc[mt][nt][1] + ad[1] + at[nt] * uw[1]);
            pk.z = f2bf(acc[mt][nt][2] + ad[2] + at[nt] * uw[2]);
            pk.w = f2bf(acc[mt][nt][3] + ad[3] + at[nt] * uw[3]);
            *(ushort4*)(et + (size_t)(b * HWSZ + hw0 + nt * 16 + l15) * 256 + cb) = pk;
        }
    }
}

// ---------------- K4: conv3x3 implicit-GEMM MFMA + BN + tanh + v-dot ------------
// v7: EXACT v1 schedule (best measured: 84.4us, 13 waves/CU, VGPR 60, no
// spills) with ONE change: Ls layout 264-pad -> linear 256/row + granule XOR
// swizzle (g ^= row&7) on BOTH ds_write and ds_read (same involution). Kills
// the 4-way bank aliasing of the 264-stride (rows r and r+8 hit identical
// banks). LDS 39.4 -> 38.1 KB (4 blocks/CU headroom). Grid (h, c-half, b).
__global__ __launch_bounds__(256) void k_conv(
    const unsigned short* __restrict__ et, const unsigned short* __restrict__ wr,
    const float* __restrict__ cs, const float* __restrict__ csh,
    const float* __restrict__ v_w, float* __restrict__ e_out)
{
    __shared__ __align__(16) unsigned short Ls[66 * 256];  // [pixel][ci], swizzled
    __shared__ float red[64][17];
    int t = threadIdx.x;
    int h = blockIdx.x, c0 = blockIdx.y * 128, b = blockIdx.z;
    int wv = t >> 6, l15 = t & 15, quad = (t >> 4) & 3;
    f32x4 acc[2][4];
    #pragma unroll
    for (int i = 0; i < 2; ++i)
        #pragma unroll
        for (int j = 0; j < 4; ++j) acc[i][j] = (f32x4)0.f;

    for (int dy = 0; dy < 3; ++dy) {
        int hr = h + dy - 1;
        if ((unsigned)hr >= (unsigned)HH) continue;   // block-uniform
        __syncthreads();
        const unsigned short* rowp = et + (size_t)(b * HH + hr) * WW * 256;
        for (int idx = t; idx < 2112; idx += 256) {   // 66 pixels x 32 granules
            int p = idx >> 5, s = idx & 31;
            short8 v;
            if (p == 0 || p == 65) v = (short8)0;
            else v = *(const short8*)(rowp + (p - 1) * 256 + s * 8);
            *(short8*)(Ls + p * 256 + ((s ^ (p & 7)) << 3)) = v;
        }
        __syncthreads();
        for (int dx = 0; dx < 3; ++dx) {
            int tap = dy * 3 + dx;
            const unsigned short* wrt = wr + (size_t)tap * 65536;
            #pragma unroll
            for (int kc = 0; kc < 8; ++kc) {
                short8 af[2], bfr[4];
                #pragma unroll
                for (int mt = 0; mt < 2; ++mt)
                    af[mt] = *(const short8*)(wrt +
                        (size_t)(c0 + wv * 32 + mt * 16 + l15) * 256 + kc * 32 + quad * 8);
                int g0 = kc * 4 + quad;
                #pragma unroll
                for (int nt = 0; nt < 4; ++nt) {
                    int wrow = nt * 16 + l15 + dx;     // 0..65, pads zero
                    bfr[nt] = *(const short8*)(Ls + wrow * 256 + ((g0 ^ (wrow & 7)) << 3));
                }
                #pragma unroll
                for (int mt = 0; mt < 2; ++mt)
                    #pragma unroll
                    for (int nt = 0; nt < 4; ++nt)
                        acc[mt][nt] = __builtin_amdgcn_mfma_f32_16x16x32_bf16(
                            af[mt], bfr[nt], acc[mt][nt], 0, 0, 0);
            }
        }
    }
    // epilogue: y = acc*cs + csh; partial e = sum tanh(y)*v_w over this lane's c
    float p[4] = {0.f, 0.f, 0.f, 0.f};
    #pragma unroll
    for (int mt = 0; mt < 2; ++mt) {
        int cb = c0 + wv * 32 + mt * 16 + quad * 4;
        #pragma unroll
        for (int r = 0; r < 4; ++r) {
            float sc = cs[cb + r], sh = csh[cb + r], vw = v_w[cb + r];
            #pragma unroll
            for (int nt = 0; nt < 4; ++nt) {
                float x = acc[mt][nt][r] * sc + sh;
                p[nt] += tanhf(x) * vw;
            }
        }
    }
    __syncthreads();
    #pragma unroll
    for (int nt = 0; nt < 4; ++nt) red[nt * 16 + l15][wv * 4 + quad] = p[nt];
    __syncthreads();
    if (t < 64) {
        float s = 0.f;
        #pragma unroll
        for (int i = 0; i < 16; ++i) s += red[t][i];
        atomicAdd(&e_out[(b * HH + h) * WW + t], s);   // two c-halves accumulate
    }
}

// ---------------- K5+K6 fused: softmax(e)->alpha (LDS) + ct reduction -----------
__global__ __launch_bounds__(256) void k_ctalpha(
    const float* __restrict__ enc, const float* __restrict__ e_acc,
    const float* __restrict__ v_b,
    const int* __restrict__ h_mask, const int* __restrict__ w_mask,
    float* __restrict__ alpha_out, float* __restrict__ ct)
{
    __shared__ float a_s[HWSZ];
    __shared__ float rbuf[4];
    int b = blockIdx.y, cg = blockIdx.x, t = threadIdx.x;
    int hm = h_mask[b], wm = w_mask[b];
    float vb = v_b[0];
    float vals[8];
    float psum = 0.f;
    #pragma unroll
    for (int u = 0; u < 8; ++u) {
        int s = u * 256 + t;
        int h = s >> 6, w = s & 63;
        float e = e_acc[b * HWSZ + s] + vb;
        float ex = (h < hm && w < wm) ? expf(e) : 0.f;
        vals[u] = ex;
        psum += ex;
    }
    for (int off = 1; off < 64; off <<= 1) psum += __shfl_xor(psum, off, 64);
    if ((t & 63) == 0) rbuf[t >> 6] = psum;
    __syncthreads();
    float inv = 1.f / (rbuf[0] + rbuf[1] + rbuf[2] + rbuf[3] + 1e-8f);
    #pragma unroll
    for (int u = 0; u < 8; ++u) {
        int s = u * 256 + t;
        float a = vals[u] * inv;
        a_s[s] = a;
        if (cg == 0) alpha_out[b * HWSZ + s] = a;
    }
    __syncthreads();
    int wave = t >> 6, lane = t & 63;
    int c = cg * 4 + wave;
    const float* ep = enc + ((size_t)(b * ENC + c)) * HWSZ;
    float s = 0.f;
    for (int i = lane; i < HWSZ; i += 64) s += ep[i] * a_s[i];
    for (int off = 32; off; off >>= 1) s += __shfl_down(s, off, 64);
    if (lane == 0) ct[b * ENC + c] = s;
}

// ---------------- K7a: gi/gh for GRU2, split-K-16 (768 blocks) ------------------
__global__ __launch_bounds__(256) void k_gru2a(
    const float* __restrict__ ct, const float* __restrict__ st,
    const float* __restrict__ w_ih, const float* __restrict__ w_hh,
    const float* __restrict__ b_ih, const float* __restrict__ b_hh,
    float* __restrict__ gi, float* __restrict__ gh)
{
    int gid = blockIdx.x * 256 + threadIdx.x;
    int o = gid >> 4, l = gid & 15;
    int j = o >> 4, b = o & 15;
    float si = dotk<16>(w_ih + (size_t)j * ENC, ct + b * ENC, l);
    float sh = dotk<4>(w_hh + (size_t)j * 256, st + b * 256, l);
    si = red16(si); sh = red16(sh);
    if (l == 0) {
        gi[j * 16 + b] = si + b_ih[j];
        gh[j * 16 + b] = sh + b_hh[j];
    }
}

// ---------------- K7b: GRU2 gates -> h2 / hidden_next ---------------------------
__global__ __launch_bounds__(256) void k_gates2(
    const float* __restrict__ st, const float* __restrict__ gi,
    const float* __restrict__ gh, float* __restrict__ h2,
    float* __restrict__ out_hidden)
{
    int b = blockIdx.x, i = threadIdx.x;
    float r = sigm(gi[i * 16 + b] + gh[i * 16 + b]);
    float z = sigm(gi[(256 + i) * 16 + b] + gh[(256 + i) * 16 + b]);
    float n = tanhf(gi[(512 + i) * 16 + b] + r * gh[(512 + i) * 16 + b]);
    float v = (1.f - z) * n + z * st[b * 256 + i];
    h2[b * 256 + i] = v;
    out_hidden[b * 256 + i] = v;
}

// ---------------- K8: pre = h2@fc2^T + emb@emb2^T + ct@wc^T, split-K-16 ---------
__global__ __launch_bounds__(256) void k_pre(
    const float* __restrict__ h2, const float* __restrict__ emb,
    const float* __restrict__ ct,
    const float* __restrict__ fc2_w, const float* __restrict__ fc2_b,
    const float* __restrict__ emb2_w, const float* __restrict__ emb2_b,
    const float* __restrict__ wc_w, const float* __restrict__ wc_b,
    float* __restrict__ pre)
{
    int gid = blockIdx.x * 256 + threadIdx.x;  // 128 blocks: 128j*16b*16l
    int o = gid >> 4, l = gid & 15;
    int j = o >> 4, b = o & 15;
    float s = dotk<4>(fc2_w + (size_t)j * 256, h2 + b * 256, l)
            + dotk<4>(emb2_w + (size_t)j * 256, emb + b * 256, l)
            + dotk<16>(wc_w + (size_t)j * ENC, ct + b * ENC, l);
    s = red16(s);
    if (l == 0) pre[b * 128 + j] = s + fc2_b[j] + emb2_b[j] + wc_b[j];
}

// ---------------- K9: logits = pre @ out_w^T + out_b, split-K-16 ----------------
__global__ __launch_bounds__(256) void k_logits(
    const float* __restrict__ pre, const float* __restrict__ out_w,
    const float* __restrict__ out_b, float* __restrict__ logits)
{
    int gid = blockIdx.x * 256 + threadIdx.x;  // 5000 blocks: 5000j*16b*16l
    int o = gid >> 4, l = gid & 15;
    int j = o >> 4, b = o & 15;
    float s = dotk<2>(out_w + (size_t)j * 128, pre + b * 128, l);
    s = red16(s);
    if (l == 0) logits[b * VOCAB + j] = s + out_b[j];
}

// ---------------- K10: log_softmax ----------------------------------------------
__global__ __launch_bounds__(256) void k_lsm(
    const float* __restrict__ logits, float* __restrict__ out)
{
    __shared__ float buf[VOCAB];
    __shared__ float rbuf[4];
    int b = blockIdx.x, t = threadIdx.x;
    float mx = -1e30f;
    for (int s = t; s < VOCAB; s += 256) {
        float v = logits[b * VOCAB + s];
        buf[s] = v;
        mx = fmaxf(mx, v);
    }
    for (int off = 1; off < 64; off <<= 1) mx = fmaxf(mx, __shfl_xor(mx, off, 64));
    if ((t & 63) == 0) rbuf[t >> 6] = mx;
    __syncthreads();
    mx = fmaxf(fmaxf(rbuf[0], rbuf[1]), fmaxf(rbuf[2], rbuf[3]));
    __syncthreads();
    float se = 0.f;
    for (int s = t; s < VOCAB; s += 256) se += expf(buf[s] - mx);
    for (int off = 1; off < 64; off <<= 1) se += __shfl_xor(se, off, 64);
    if ((t & 63) == 0) rbuf[t >> 6] = se;
    __syncthreads();
    float lse = mx + logf(rbuf[0] + rbuf[1] + rbuf[2] + rbuf[3]);
    for (int s = t; s < VOCAB; s += 256) out[b * VOCAB + s] = buf[s] - lse;
}

extern "C" void kernel_launch(void* const* d_in, const int* in_sizes, int n_in,
                              void* d_out, int out_size, void* d_ws, size_t ws_size,
                              hipStream_t stream)
{
    const int*   input_a      = (const int*)d_in[0];
    const float* input_hidden = (const float*)d_in[1];
    const float* enc          = (const float*)d_in[2];
    const float* att_in       = (const float*)d_in[3];
    const float* dec_att      = (const float*)d_in[4];
    const int*   h_mask       = (const int*)d_in[5];
    const int*   w_mask       = (const int*)d_in[6];
    const float* emb_w        = (const float*)d_in[11];
    const float* g1_wih       = (const float*)d_in[12];
    const float* g1_whh       = (const float*)d_in[13];
    const float* g1_bih       = (const float*)d_in[14];
    const float* g1_bhh       = (const float*)d_in[15];
    const float* fc1_w        = (const float*)d_in[16];
    const float* fc1_b        = (const float*)d_in[17];
    const float* g2_wih       = (const float*)d_in[18];
    const float* g2_whh       = (const float*)d_in[19];
    const float* g2_bih       = (const float*)d_in[20];
    const float* g2_bhh       = (const float*)d_in[21];
    const float* out_w        = (const float*)d_in[22];
    const float* out_b        = (const float*)d_in[23];
    const float* emb2_w       = (const float*)d_in[24];
    const float* emb2_b       = (const float*)d_in[25];
    const float* c1w          = (const float*)d_in[26];
    const float* c1b          = (const float*)d_in[27];
    const float* ctw          = (const float*)d_in[28];
    const float* ctb          = (const float*)d_in[29];
    const float* fc2_w        = (const float*)d_in[30];
    const float* fc2_b        = (const float*)d_in[31];
    const float* ua_w         = (const float*)d_in[32];
    const float* ua_b         = (const float*)d_in[33];
    const float* uf_w         = (const float*)d_in[34];
    const float* uf_b         = (const float*)d_in[35];
    const float* v_w          = (const float*)d_in[36];
    const float* v_b          = (const float*)d_in[37];
    const float* wc_w         = (const float*)d_in[38];
    const float* wc_b         = (const float*)d_in[39];
    const float* bn_g         = (const float*)d_in[40];
    const float* bn_b         = (const float*)d_in[41];
    const float* bn_rm        = (const float*)d_in[42];
    const float* bn_rv        = (const float*)d_in[43];

    // output layout: log_softmax(16x5000) | hidden_next(16x256) | alpha(16x2048) | att_sum(16x2048)
    float* out        = (float*)d_out;
    float* out_logits = out;
    float* out_hidden = out + 80000;
    float* out_alpha  = out + 84096;
    float* out_attsum = out + 116864;

    // workspace layout
    char* ws = (char*)d_ws;
    unsigned short* et_t  = (unsigned short*)ws;                 // 16.78 MB (NHWC bf16)
    unsigned short* ua_bf = (unsigned short*)(ws + 16777216);    // 0.52 MB
    unsigned short* w_r   = (unsigned short*)(ws + 17301504);    // 1.18 MB
    float* f      = (float*)(ws + 18481152);
    float* st     = f;             // 4096
    float* embv   = f + 4096;      // 4096
    float* addc   = f + 8192;      // 4096
    float* e_ws   = f + 12288;     // 32768
    float* ct     = f + 45056;     // 16384
    float* h2     = f + 61440;     // 4096
    float* pre    = f + 65536;     // 2048
    float* logits = f + 67584;     // 80000
    float* gi1    = f + 147584;    // 12288
    float* gh1    = f + 159872;    // 12288
    float* gi2    = f + 172160;    // 12288
    float* gh2    = f + 184448;    // 12288
    float* cs     = f + 196736;    // 256
    float* csh    = f + 196992;    // 256

    k_prep<<<2305, 256, 0, stream>>>(ua_w, ua_bf, ctw, w_r,
                                     att_in, dec_att, c1w, c1b, out_attsum,
                                     ctb, bn_g, bn_b, bn_rm, bn_rv, cs, csh,
                                     input_a, input_hidden, emb_w,
                                     g1_wih, g1_whh, g1_bih, g1_bhh, gi1, gh1,
                                     e_ws);
    k_frontbc<<<16, 256, 0, stream>>>(input_a, emb_w, input_hidden, gi1, gh1,
                                      fc1_w, fc1_b, ua_b, uf_b, st, embv, addc);

    k_et<<<dim3(64, 16), 256, 0, stream>>>(enc, ua_bf, addc, uf_w, out_attsum, et_t);
    k_conv<<<dim3(32, 2, 16), 256, 0, stream>>>(et_t, w_r, cs, csh, v_w, e_ws);

    k_ctalpha<<<dim3(256, 16), 256, 0, stream>>>(enc, e_ws, v_b, h_mask, w_mask,
                                                 out_alpha, ct);
    k_gru2a<<<768, 256, 0, stream>>>(ct, st, g2_wih, g2_whh, g2_bih, g2_bhh, gi2, gh2);
    k_gates2<<<16, 256, 0, stream>>>(st, gi2, gh2, h2, out_hidden);
    k_pre<<<128, 256, 0, stream>>>(h2, embv, ct, fc2_w, fc2_b, emb2_w, emb2_b,
                                   wc_w, wc_b, pre);
    k_logits<<<5000, 256, 0, stream>>>(pre, out_w, out_b, logits);
    k_lsm<<<16, 256, 0, stream>>>(logits, out_logits);
}

// Round 8
// 448.016 us; speedup vs baseline: 1.0609x; 1.0144x over previous
//
#include <hip/hip_runtime.h>
#include <hip/hip_bf16.h>

#define HH 32
#define WW 64
#define HWSZ 2048
#define ENC 1024
#define VOCAB 5000

typedef __attribute__((ext_vector_type(8))) short short8;
typedef __attribute__((ext_vector_type(4))) short short4v;
typedef __attribute__((ext_vector_type(4))) float f32x4;

#if defined(__has_builtin)
#if __has_builtin(__builtin_amdgcn_global_load_lds)
#define HAVE_GLD_LDS 1
#endif
#endif

__device__ __forceinline__ float sigm(float x) { return 1.0f / (1.0f + expf(-x)); }

__device__ __forceinline__ unsigned short f2bf(float x) {
    unsigned u = __float_as_uint(x);
    unsigned r = (u + 0x7fff + ((u >> 16) & 1)) >> 16;
    return (unsigned short)r;
}

#ifdef HAVE_GLD_LDS
__device__ __forceinline__ void gld_lds16(const unsigned short* g, unsigned short* l) {
    __builtin_amdgcn_global_load_lds(
        (const __attribute__((address_space(1))) void*)g,
        (__attribute__((address_space(3))) void*)l,
        16, 0, 0);
}
#endif

// split-K-16 helpers: lane l of a 16-lane group covers k = i*64 + l*4 .. +3
template <int NI>
__device__ __forceinline__ float dotk(const float* __restrict__ w,
                                      const float* __restrict__ x, int l) {
    float s = 0.f;
    #pragma unroll
    for (int i = 0; i < NI; ++i) {
        f32x4 wv = *(const f32x4*)(w + i * 64 + l * 4);
        f32x4 xv = *(const f32x4*)(x + i * 64 + l * 4);
        s += wv.x * xv.x + wv.y * xv.y + wv.z * xv.z + wv.w * xv.w;
    }
    return s;
}
__device__ __forceinline__ float red16(float s) {
    s += __shfl_xor(s, 1, 64);
    s += __shfl_xor(s, 2, 64);
    s += __shfl_xor(s, 4, 64);
    s += __shfl_xor(s, 8, 64);
    return s;
}

// ---------------- K0: fused prep: ua->bf16 | wr | attsum | coef | GRU1-a | e=0 --
__global__ __launch_bounds__(256) void k_prep(
    const float* __restrict__ ua_w, unsigned short* __restrict__ ub,
    const float* __restrict__ cw, unsigned short* __restrict__ wr,
    const float* __restrict__ att_in, const float* __restrict__ dec,
    const float* __restrict__ c1w, const float* __restrict__ c1b,
    float* __restrict__ out_attsum,
    const float* __restrict__ wb, const float* __restrict__ g,
    const float* __restrict__ bb, const float* __restrict__ rm,
    const float* __restrict__ rv, float* __restrict__ cs, float* __restrict__ csh,
    const int* __restrict__ input_a, const float* __restrict__ input_hidden,
    const float* __restrict__ emb_w,
    const float* __restrict__ w_ih, const float* __restrict__ w_hh,
    const float* __restrict__ b_ih, const float* __restrict__ b_hh,
    float* __restrict__ gi, float* __restrict__ gh,
    float* __restrict__ e_zero)
{
    int blk = blockIdx.x, t = threadIdx.x;
    if (blk < 1024) {                       // ua_w fp32 -> bf16
        int idx = blk * 256 + t;
        ub[idx] = f2bf(ua_w[idx]);
    } else if (blk < 1280) {                // convtan_w -> w_r[tap][o][ci] bf16
        int idx = (blk - 1024) * 256 + t;   // 65536 = (o,ci)
        const float* p = cw + (size_t)idx * 9;
        #pragma unroll
        for (int k = 0; k < 9; ++k) wr[k * 65536 + idx] = f2bf(p[k]);
    } else if (blk < 1408) {                // att_sum = attention_sum + conv1(dec)
        int idx = (blk - 1280) * 256 + t;   // < 32768
        int b = idx >> 11, hw = idx & 2047;
        int h = hw >> 6, w = hw & 63;
        float s = c1b[0];
        #pragma unroll
        for (int dy = 0; dy < 3; ++dy) {
            int hh = h + dy - 1;
            if ((unsigned)hh < (unsigned)HH) {
                #pragma unroll
                for (int dx = 0; dx < 3; ++dx) {
                    int wi = w + dx - 1;
                    if ((unsigned)wi < (unsigned)WW)
                        s += dec[b * HWSZ + hh * WW + wi] * c1w[dy * 3 + dx];
                }
            }
        }
        out_attsum[idx] = att_in[idx] + s;
    } else if (blk == 1408) {               // BN coef fold
        int c = t;
        float s = g[c] * rsqrtf(rv[c] + 1e-5f);
        cs[c] = s;
        csh[c] = (wb[c] - rm[c]) * s + bb[c];
    } else if (blk < 2177) {                // GRU1 gi/gh split-K (768 blocks)
        int gid = (blk - 1409) * 256 + t;   // 196608 = 768j * 16b * 16l
        int o = gid >> 4, l = gid & 15;
        int j = o >> 4, b = o & 15;
        int ia = input_a[b];
        float si = dotk<4>(w_ih + (size_t)j * 256, emb_w + (size_t)ia * 256, l);
        float sh = dotk<4>(w_hh + (size_t)j * 256, input_hidden + b * 256, l);
        si = red16(si); sh = red16(sh);
        if (l == 0) {
            gi[j * 16 + b] = si + b_ih[j];
            gh[j * 16 + b] = sh + b_hh[j];
        }
    } else {                                // zero e accumulator (128 blocks)
        e_zero[(blk - 2177) * 256 + t] = 0.f;
    }
}

// ---------------- K1b: GRU1 gates + emb passthrough + fc1 -> addc (fused) -------
__global__ __launch_bounds__(256) void k_frontbc(
    const int* __restrict__ input_a, const float* __restrict__ emb_w,
    const float* __restrict__ input_hidden,
    const float* __restrict__ gi, const float* __restrict__ gh,
    const float* __restrict__ fc1_w, const float* __restrict__ fc1_b,
    const float* __restrict__ ua_b, const float* __restrict__ uf_b,
    float* __restrict__ st, float* __restrict__ embv, float* __restrict__ addc)
{
    __shared__ float st_s[256];
    int b = blockIdx.x, i = threadIdx.x;
    float r = sigm(gi[i * 16 + b] + gh[i * 16 + b]);
    float z = sigm(gi[(256 + i) * 16 + b] + gh[(256 + i) * 16 + b]);
    float n = tanhf(gi[(512 + i) * 16 + b] + r * gh[(512 + i) * 16 + b]);
    float h0 = input_hidden[b * 256 + i];
    float v = (1.f - z) * n + z * h0;
    st_s[i] = v;
    st[b * 256 + i] = v;
    embv[b * 256 + i] = emb_w[(size_t)input_a[b] * 256 + i];
    __syncthreads();
    int c = i;
    const float* w = fc1_w + (size_t)c * 256;
    float acc = 0.f;
    for (int k = 0; k < 256; ++k) acc += st_s[k] * w[k];
    addc[b * 256 + c] = acc + fc1_b[c] + ua_b[c] + uf_b[c];
}

// ---------------- K3: et-GEMM via MFMA, N=32/block, grid 64x16 ------------------
// out[c=256][hw=32/block] = ua[c][k=1024] @ enc[k][hw]; NHWC bf16 out.
// Mask-skip: et only consumed by conv for rows <= h_mask[b], pixels <= w_mask[b].
__global__ __launch_bounds__(256) void k_et(
    const float* __restrict__ enc, const unsigned short* __restrict__ ua_bf,
    const float* __restrict__ addc, const float* __restrict__ uf_w,
    const float* __restrict__ attsum,
    const int* __restrict__ h_mask, const int* __restrict__ w_mask,
    unsigned short* __restrict__ et)
{
    // As[c=256][64k] bf16, swizzled: slot kq holds k-octet (kq ^ (c&7)).  32 KB
    // Bs[p=32][64k]  bf16, same swizzle on p.                              4 KB
    __shared__ __align__(16) unsigned short As[256 * 64];
    __shared__ __align__(16) unsigned short Bs[32 * 64];
    int t = threadIdx.x;
    int hw0 = blockIdx.x * 32, b = blockIdx.y;
    {   // block-uniform mask skip: this 32-pixel chunk feeds no live conv output
        int row = blockIdx.x >> 1, w0 = (blockIdx.x & 1) * 32;
        if (row > h_mask[b] || w0 > w_mask[b]) return;
    }
    int wv = t >> 6;
    int l15 = t & 15, quad = (t >> 4) & 3;
    int xb = l15 & 7;
    f32x4 acc[4][2];
    #pragma unroll
    for (int i = 0; i < 4; ++i)
        #pragma unroll
        for (int j = 0; j < 2; ++j) acc[i][j] = (f32x4)0.f;

    // B staging role: pixel p (0..31), k-octet g3 (0..7) within BK=64
    int p = t & 31, g3 = t >> 5;
    const float* encb = enc + (size_t)b * ENC * HWSZ + hw0 + p;

    float pfv[8];
    {   // prologue prefetch for k0 = 0
        const float* ep = encb + (size_t)(g3 * 8) * HWSZ;
        #pragma unroll
        for (int j = 0; j < 8; ++j) pfv[j] = ep[(size_t)j * HWSZ];
    }

    for (int k0 = 0; k0 < ENC; k0 += 64) {
        // convert current B subtile, then immediately issue next prefetch
        short8 bv;
        #pragma unroll
        for (int j = 0; j < 8; ++j) bv[j] = (short)f2bf(pfv[j]);
        if (k0 + 64 < ENC) {
            const float* ep = encb + (size_t)(k0 + 64 + g3 * 8) * HWSZ;
            #pragma unroll
            for (int j = 0; j < 8; ++j) pfv[j] = ep[(size_t)j * HWSZ];
        }
        __syncthreads();   // all waves done reading LDS from previous k-step

        // A-tile: 2048 slots (c=s>>3, kq=s&7); dest linear, source pre-swizzled
        #pragma unroll
        for (int i = 0; i < 8; ++i) {
            int s = t + 256 * i;
            int c = s >> 3, kq = s & 7;
            const unsigned short* src =
                ua_bf + (size_t)c * ENC + k0 + ((kq ^ (c & 7)) << 3);
#ifdef HAVE_GLD_LDS
            gld_lds16(src, As + (size_t)(wv * 64 + 256 * i) * 8);
#else
            *(uint4*)(As + (size_t)s * 8) = *(const uint4*)src;
#endif
        }
        // B-tile: swizzled ds_write_b128
        *(short8*)(Bs + p * 64 + ((g3 ^ (p & 7)) << 3)) = bv;
        __syncthreads();   // drains gld_lds (vmcnt) + ds_write (lgkm)

        #pragma unroll
        for (int kk = 0; kk < 2; ++kk) {
            short8 af[4], bfr[2];
            #pragma unroll
            for (int mt = 0; mt < 4; ++mt) {
                int c = wv * 64 + mt * 16 + l15;
                af[mt] = *(const short8*)(As + c * 64 + (((kk * 4 + quad) ^ xb) << 3));
            }
            #pragma unroll
            for (int nt = 0; nt < 2; ++nt) {
                int n = nt * 16 + l15;
                bfr[nt] = *(const short8*)(Bs + n * 64 + (((kk * 4 + quad) ^ xb) << 3));
            }
            #pragma unroll
            for (int mt = 0; mt < 4; ++mt)
                #pragma unroll
                for (int nt = 0; nt < 2; ++nt)
                    acc[mt][nt] = __builtin_amdgcn_mfma_f32_16x16x32_bf16(
                        af[mt], bfr[nt], acc[mt][nt], 0, 0, 0);
        }
    }
    // epilogue: + addc[c] + attsum[hw]*uf_w[c], store NHWC bf16
    float at[2];
    #pragma unroll
    for (int nt = 0; nt < 2; ++nt) at[nt] = attsum[b * HWSZ + hw0 + nt * 16 + l15];
    #pragma unroll
    for (int mt = 0; mt < 4; ++mt) {
        int cb = wv * 64 + mt * 16 + quad * 4;
        float ad[4], uw[4];
        #pragma unroll
        for (int r = 0; r < 4; ++r) { ad[r] = addc[b * 256 + cb + r]; uw[r] = uf_w[cb + r]; }
        #pragma unroll
        for (int nt = 0; nt < 2; ++nt) {
            ushort4 pk;
            pk.x = f2bf(acc[mt][nt][0] + ad[0] + at[nt] * uw[0]);
            pk.y = f2bf(acc[mt][nt][1] + ad[1] + at[nt] * uw[1]);
            pk.z = f2bf(acc[mt][nt][2] + ad[2] + at[nt] * uw[2]);
            pk.w = f2bf(acc[mt][nt][3] + ad[3] + at[nt] * uw[3]);
            *(ushort4*)(et + (size_t)(b * HWSZ + hw0 + nt * 16 + l15) * 256 + cb) = pk;
        }
    }
}

// ---------------- K4: conv3x3 implicit-GEMM MFMA + BN + tanh + v-dot ------------
// v8: EXACT v1 schedule/layout (best measured 84.4us) + mask-skip:
//  - block exits if h >= h_mask[b] (output row fully masked; e_ws pre-zeroed)
//  - nt loop capped at ntmax = ceil(w_mask/16); staging capped at pxmax rows.
// Garbage et beyond (hm,wm) only feeds masked outputs (k_ctalpha predicate
// never exponentiates them). Grid (h, c-half, b) unchanged.
__global__ __launch_bounds__(256) void k_conv(
    const unsigned short* __restrict__ et, const unsigned short* __restrict__ wr,
    const float* __restrict__ cs, const float* __restrict__ csh,
    const float* __restrict__ v_w,
    const int* __restrict__ h_mask, const int* __restrict__ w_mask,
    float* __restrict__ e_out)
{
    __shared__ unsigned short Ls[66 * 264];  // [pixel 0..65][ci 256 pad->264]
    __shared__ float red[64][17];
    int t = threadIdx.x;
    int h = blockIdx.x, c0 = blockIdx.y * 128, b = blockIdx.z;
    if (h >= h_mask[b]) return;              // block-uniform: row masked out
    int wm = w_mask[b];
    int ntmax = (wm + 15) >> 4;              // 1..4: pixel groups with live output
    int pxmax = ntmax * 16 + 2;              // staged Ls rows needed (<= 66)
    int wv = t >> 6, l15 = t & 15, quad = (t >> 4) & 3;
    f32x4 acc[2][4];
    #pragma unroll
    for (int i = 0; i < 2; ++i)
        #pragma unroll
        for (int j = 0; j < 4; ++j) acc[i][j] = (f32x4)0.f;

    for (int dy = 0; dy < 3; ++dy) {
        int hr = h + dy - 1;
        if ((unsigned)hr >= (unsigned)HH) continue;   // block-uniform
        __syncthreads();
        const unsigned short* rowp = et + (size_t)(b * HH + hr) * WW * 256;
        for (int idx = t; idx < pxmax * 32; idx += 256) {  // pixels x 32 chunks
            int p = idx >> 5, s = idx & 31;
            short8 v;
            if (p == 0 || p == 65) v = (short8)0;
            else v = *(const short8*)(rowp + (p - 1) * 256 + s * 8);
            *(short8*)(Ls + p * 264 + s * 8) = v;
        }
        __syncthreads();
        for (int dx = 0; dx < 3; ++dx) {
            int tap = dy * 3 + dx;
            const unsigned short* wrt = wr + (size_t)tap * 65536;
            #pragma unroll
            for (int kc = 0; kc < 8; ++kc) {
                short8 af[2], bfr[4];
                #pragma unroll
                for (int mt = 0; mt < 2; ++mt)
                    af[mt] = *(const short8*)(wrt +
                        (size_t)(c0 + wv * 32 + mt * 16 + l15) * 256 + kc * 32 + quad * 8);
                #pragma unroll
                for (int nt = 0; nt < 4; ++nt) {
                    if (nt < ntmax) {
                        int wrow = nt * 16 + l15 + dx;     // 0..65, pads zero
                        bfr[nt] = *(const short8*)(Ls + wrow * 264 + kc * 32 + quad * 8);
                    }
                }
                #pragma unroll
                for (int mt = 0; mt < 2; ++mt)
                    #pragma unroll
                    for (int nt = 0; nt < 4; ++nt)
                        if (nt < ntmax)
                            acc[mt][nt] = __builtin_amdgcn_mfma_f32_16x16x32_bf16(
                                af[mt], bfr[nt], acc[mt][nt], 0, 0, 0);
            }
        }
    }
    // epilogue: y = acc*cs + csh; partial e = sum tanh(y)*v_w over this lane's c
    float p[4] = {0.f, 0.f, 0.f, 0.f};
    #pragma unroll
    for (int mt = 0; mt < 2; ++mt) {
        int cb = c0 + wv * 32 + mt * 16 + quad * 4;
        #pragma unroll
        for (int r = 0; r < 4; ++r) {
            float sc = cs[cb + r], sh = csh[cb + r], vw = v_w[cb + r];
            #pragma unroll
            for (int nt = 0; nt < 4; ++nt) {
                if (nt < ntmax) {
                    float x = acc[mt][nt][r] * sc + sh;
                    p[nt] += tanhf(x) * vw;
                }
            }
        }
    }
    __syncthreads();
    #pragma unroll
    for (int nt = 0; nt < 4; ++nt) red[nt * 16 + l15][wv * 4 + quad] = p[nt];
    __syncthreads();
    if (t < 64) {
        float s = 0.f;
        #pragma unroll
        for (int i = 0; i < 16; ++i) s += red[t][i];
        atomicAdd(&e_out[(b * HH + h) * WW + t], s);   // two c-halves accumulate
    }
}

// ---------------- K5+K6 fused: softmax(e)->alpha (LDS) + ct reduction -----------
__global__ __launch_bounds__(256) void k_ctalpha(
    const float* __restrict__ enc, const float* __restrict__ e_acc,
    const float* __restrict__ v_b,
    const int* __restrict__ h_mask, const int* __restrict__ w_mask,
    float* __restrict__ alpha_out, float* __restrict__ ct)
{
    __shared__ float a_s[HWSZ];
    __shared__ float rbuf[4];
    int b = blockIdx.y, cg = blockIdx.x, t = threadIdx.x;
    int hm = h_mask[b], wm = w_mask[b];
    float vb = v_b[0];
    float vals[8];
    float psum = 0.f;
    #pragma unroll
    for (int u = 0; u < 8; ++u) {
        int s = u * 256 + t;
        int h = s >> 6, w = s & 63;
        float e = e_acc[b * HWSZ + s] + vb;
        float ex = (h < hm && w < wm) ? expf(e) : 0.f;
        vals[u] = ex;
        psum += ex;
    }
    for (int off = 1; off < 64; off <<= 1) psum += __shfl_xor(psum, off, 64);
    if ((t & 63) == 0) rbuf[t >> 6] = psum;
    __syncthreads();
    float inv = 1.f / (rbuf[0] + rbuf[1] + rbuf[2] + rbuf[3] + 1e-8f);
    #pragma unroll
    for (int u = 0; u < 8; ++u) {
        int s = u * 256 + t;
        float a = vals[u] * inv;
        a_s[s] = a;
        if (cg == 0) alpha_out[b * HWSZ + s] = a;
    }
    __syncthreads();
    int wave = t >> 6, lane = t & 63;
    int c = cg * 4 + wave;
    const float* ep = enc + ((size_t)(b * ENC + c)) * HWSZ;
    float s = 0.f;
    int imax = hm * 64;                       // a_s == 0 beyond masked rows
    for (int i = lane; i < imax; i += 64) s += ep[i] * a_s[i];
    for (int off = 32; off; off >>= 1) s += __shfl_down(s, off, 64);
    if (lane == 0) ct[b * ENC + c] = s;
}

// ---------------- K7a: gi/gh for GRU2, split-K-16 (768 blocks) ------------------
__global__ __launch_bounds__(256) void k_gru2a(
    const float* __restrict__ ct, const float* __restrict__ st,
    const float* __restrict__ w_ih, const float* __restrict__ w_hh,
    const float* __restrict__ b_ih, const float* __restrict__ b_hh,
    float* __restrict__ gi, float* __restrict__ gh)
{
    int gid = blockIdx.x * 256 + threadIdx.x;
    int o = gid >> 4, l = gid & 15;
    int j = o >> 4, b = o & 15;
    float si = dotk<16>(w_ih + (size_t)j * ENC, ct + b * ENC, l);
    float sh = dotk<4>(w_hh + (size_t)j * 256, st + b * 256, l);
    si = red16(si); sh = red16(sh);
    if (l == 0) {
        gi[j * 16 + b] = si + b_ih[j];
        gh[j * 16 + b] = sh + b_hh[j];
    }
}

// ---------------- K7b: GRU2 gates -> h2 / hidden_next ---------------------------
__global__ __launch_bounds__(256) void k_gates2(
    const float* __restrict__ st, const float* __restrict__ gi,
    const float* __restrict__ gh, float* __restrict__ h2,
    float* __restrict__ out_hidden)
{
    int b = blockIdx.x, i = threadIdx.x;
    float r = sigm(gi[i * 16 + b] + gh[i * 16 + b]);
    float z = sigm(gi[(256 + i) * 16 + b] + gh[(256 + i) * 16 + b]);
    float n = tanhf(gi[(512 + i) * 16 + b] + r * gh[(512 + i) * 16 + b]);
    float v = (1.f - z) * n + z * st[b * 256 + i];
    h2[b * 256 + i] = v;
    out_hidden[b * 256 + i] = v;
}

// ---------------- K8: pre = h2@fc2^T + emb@emb2^T + ct@wc^T, split-K-16 ---------
__global__ __launch_bounds__(256) void k_pre(
    const float* __restrict__ h2, const float* __restrict__ emb,
    const float* __restrict__ ct,
    const float* __restrict__ fc2_w, const float* __restrict__ fc2_b,
    const float* __restrict__ emb2_w, const float* __restrict__ emb2_b,
    const float* __restrict__ wc_w, const float* __restrict__ wc_b,
    float* __restrict__ pre)
{
    int gid = blockIdx.x * 256 + threadIdx.x;  // 128 blocks: 128j*16b*16l
    int o = gid >> 4, l = gid & 15;
    int j = o >> 4, b = o & 15;
    float s = dotk<4>(fc2_w + (size_t)j * 256, h2 + b * 256, l)
            + dotk<4>(emb2_w + (size_t)j * 256, emb + b * 256, l)
            + dotk<16>(wc_w + (size_t)j * ENC, ct + b * ENC, l);
    s = red16(s);
    if (l == 0) pre[b * 128 + j] = s + fc2_b[j] + emb2_b[j] + wc_b[j];
}

// ---------------- K9: logits = pre @ out_w^T + out_b, split-K-16 ----------------
__global__ __launch_bounds__(256) void k_logits(
    const float* __restrict__ pre, const float* __restrict__ out_w,
    const float* __restrict__ out_b, float* __restrict__ logits)
{
    int gid = blockIdx.x * 256 + threadIdx.x;  // 5000 blocks: 5000j*16b*16l
    int o = gid >> 4, l = gid & 15;
    int j = o >> 4, b = o & 15;
    float s = dotk<2>(out_w + (size_t)j * 128, pre + b * 128, l);
    s = red16(s);
    if (l == 0) logits[b * VOCAB + j] = s + out_b[j];
}

// ---------------- K10: log_softmax ----------------------------------------------
__global__ __launch_bounds__(256) void k_lsm(
    const float* __restrict__ logits, float* __restrict__ out)
{
    __shared__ float buf[VOCAB];
    __shared__ float rbuf[4];
    int b = blockIdx.x, t = threadIdx.x;
    float mx = -1e30f;
    for (int s = t; s < VOCAB; s += 256) {
        float v = logits[b * VOCAB + s];
        buf[s] = v;
        mx = fmaxf(mx, v);
    }
    for (int off = 1; off < 64; off <<= 1) mx = fmaxf(mx, __shfl_xor(mx, off, 64));
    if ((t & 63) == 0) rbuf[t >> 6] = mx;
    __syncthreads();
    mx = fmaxf(fmaxf(rbuf[0], rbuf[1]), fmaxf(rbuf[2], rbuf[3]));
    __syncthreads();
    float se = 0.f;
    for (int s = t; s < VOCAB; s += 256) se += expf(buf[s] - mx);
    for (int off = 1; off < 64; off <<= 1) se += __shfl_xor(se, off, 64);
    if ((t & 63) == 0) rbuf[t >> 6] = se;
    __syncthreads();
    float lse = mx + logf(rbuf[0] + rbuf[1] + rbuf[2] + rbuf[3]);
    for (int s = t; s < VOCAB; s += 256) out[b * VOCAB + s] = buf[s] - lse;
}

extern "C" void kernel_launch(void* const* d_in, const int* in_sizes, int n_in,
                              void* d_out, int out_size, void* d_ws, size_t ws_size,
                              hipStream_t stream)
{
    const int*   input_a      = (const int*)d_in[0];
    const float* input_hidden = (const float*)d_in[1];
    const float* enc          = (const float*)d_in[2];
    const float* att_in       = (const float*)d_in[3];
    const float* dec_att      = (const float*)d_in[4];
    const int*   h_mask       = (const int*)d_in[5];
    const int*   w_mask       = (const int*)d_in[6];
    const float* emb_w        = (const float*)d_in[11];
    const float* g1_wih       = (const float*)d_in[12];
    const float* g1_whh       = (const float*)d_in[13];
    const float* g1_bih       = (const float*)d_in[14];
    const float* g1_bhh       = (const float*)d_in[15];
    const float* fc1_w        = (const float*)d_in[16];
    const float* fc1_b        = (const float*)d_in[17];
    const float* g2_wih       = (const float*)d_in[18];
    const float* g2_whh       = (const float*)d_in[19];
    const float* g2_bih       = (const float*)d_in[20];
    const float* g2_bhh       = (const float*)d_in[21];
    const float* out_w        = (const float*)d_in[22];
    const float* out_b        = (const float*)d_in[23];
    const float* emb2_w       = (const float*)d_in[24];
    const float* emb2_b       = (const float*)d_in[25];
    const float* c1w          = (const float*)d_in[26];
    const float* c1b          = (const float*)d_in[27];
    const float* ctw          = (const float*)d_in[28];
    const float* ctb          = (const float*)d_in[29];
    const float* fc2_w        = (const float*)d_in[30];
    const float* fc2_b        = (const float*)d_in[31];
    const float* ua_w         = (const float*)d_in[32];
    const float* ua_b         = (const float*)d_in[33];
    const float* uf_w         = (const float*)d_in[34];
    const float* uf_b         = (const float*)d_in[35];
    const float* v_w          = (const float*)d_in[36];
    const float* v_b          = (const float*)d_in[37];
    const float* wc_w         = (const float*)d_in[38];
    const float* wc_b         = (const float*)d_in[39];
    const float* bn_g         = (const float*)d_in[40];
    const float* bn_b         = (const float*)d_in[41];
    const float* bn_rm        = (const float*)d_in[42];
    const float* bn_rv        = (const float*)d_in[43];

    // output layout: log_softmax(16x5000) | hidden_next(16x256) | alpha(16x2048) | att_sum(16x2048)
    float* out        = (float*)d_out;
    float* out_logits = out;
    float* out_hidden = out + 80000;
    float* out_alpha  = out + 84096;
    float* out_attsum = out + 116864;

    // workspace layout
    char* ws = (char*)d_ws;
    unsigned short* et_t  = (unsigned short*)ws;                 // 16.78 MB (NHWC bf16)
    unsigned short* ua_bf = (unsigned short*)(ws + 16777216);    // 0.52 MB
    unsigned short* w_r   = (unsigned short*)(ws + 17301504);    // 1.18 MB
    float* f      = (float*)(ws + 18481152);
    float* st     = f;             // 4096
    float* embv   = f + 4096;      // 4096
    float* addc   = f + 8192;      // 4096
    float* e_ws   = f + 12288;     // 32768
    float* ct     = f + 45056;     // 16384
    float* h2     = f + 61440;     // 4096
    float* pre    = f + 65536;     // 2048
    float* logits = f + 67584;     // 80000
    float* gi1    = f + 147584;    // 12288
    float* gh1    = f + 159872;    // 12288
    float* gi2    = f + 172160;    // 12288
    float* gh2    = f + 184448;    // 12288
    float* cs     = f + 196736;    // 256
    float* csh    = f + 196992;    // 256

    k_prep<<<2305, 256, 0, stream>>>(ua_w, ua_bf, ctw, w_r,
                                     att_in, dec_att, c1w, c1b, out_attsum,
                                     ctb, bn_g, bn_b, bn_rm, bn_rv, cs, csh,
                                     input_a, input_hidden, emb_w,
                                     g1_wih, g1_whh, g1_bih, g1_bhh, gi1, gh1,
                                     e_ws);
    k_frontbc<<<16, 256, 0, stream>>>(input_a, emb_w, input_hidden, gi1, gh1,
                                      fc1_w, fc1_b, ua_b, uf_b, st, embv, addc);

    k_et<<<dim3(64, 16), 256, 0, stream>>>(enc, ua_bf, addc, uf_w, out_attsum,
                                           h_mask, w_mask, et_t);
    k_conv<<<dim3(32, 2, 16), 256, 0, stream>>>(et_t, w_r, cs, csh, v_w,
                                                h_mask, w_mask, e_ws);

    k_ctalpha<<<dim3(256, 16), 256, 0, stream>>>(enc, e_ws, v_b, h_mask, w_mask,
                                                 out_alpha, ct);
    k_gru2a<<<768, 256, 0, stream>>>(ct, st, g2_wih, g2_whh, g2_bih, g2_bhh, gi2, gh2);
    k_gates2<<<16, 256, 0, stream>>>(st, gi2, gh2, h2, out_hidden);
    k_pre<<<128, 256, 0, stream>>>(h2, embv, ct, fc2_w, fc2_b, emb2_w, emb2_b,
                                   wc_w, wc_b, pre);
    k_logits<<<5000, 256, 0, stream>>>(pre, out_w, out_b, logits);
    k_lsm<<<16, 256, 0, stream>>>(logits, out_logits);
}

// Round 9
// 413.275 us; speedup vs baseline: 1.1501x; 1.0841x over previous
//
#include <hip/hip_runtime.h>
#include <hip/hip_bf16.h>

#define HH 32
#define WW 64
#define HWSZ 2048
#define ENC 1024
#define VOCAB 5000

typedef __attribute__((ext_vector_type(8))) short short8;
typedef __attribute__((ext_vector_type(4))) short short4v;
typedef __attribute__((ext_vector_type(4))) float f32x4;

#if defined(__has_builtin)
#if __has_builtin(__builtin_amdgcn_global_load_lds)
#define HAVE_GLD_LDS 1
#endif
#endif

__device__ __forceinline__ float sigm(float x) { return 1.0f / (1.0f + expf(-x)); }

__device__ __forceinline__ unsigned short f2bf(float x) {
    unsigned u = __float_as_uint(x);
    unsigned r = (u + 0x7fff + ((u >> 16) & 1)) >> 16;
    return (unsigned short)r;
}

#ifdef HAVE_GLD_LDS
__device__ __forceinline__ void gld_lds16(const unsigned short* g, unsigned short* l) {
    __builtin_amdgcn_global_load_lds(
        (const __attribute__((address_space(1))) void*)g,
        (__attribute__((address_space(3))) void*)l,
        16, 0, 0);
}
#endif

// split-K-16 helpers: lane l of a 16-lane group covers k = i*64 + l*4 .. +3
template <int NI>
__device__ __forceinline__ float dotk(const float* __restrict__ w,
                                      const float* __restrict__ x, int l) {
    float s = 0.f;
    #pragma unroll
    for (int i = 0; i < NI; ++i) {
        f32x4 wv = *(const f32x4*)(w + i * 64 + l * 4);
        f32x4 xv = *(const f32x4*)(x + i * 64 + l * 4);
        s += wv.x * xv.x + wv.y * xv.y + wv.z * xv.z + wv.w * xv.w;
    }
    return s;
}
__device__ __forceinline__ float red16(float s) {
    s += __shfl_xor(s, 1, 64);
    s += __shfl_xor(s, 2, 64);
    s += __shfl_xor(s, 4, 64);
    s += __shfl_xor(s, 8, 64);
    return s;
}

// ---------------- K0: fused prep + worklist compaction --------------------------
__global__ __launch_bounds__(256) void k_prep(
    const float* __restrict__ ua_w, unsigned short* __restrict__ ub,
    const float* __restrict__ cw, unsigned short* __restrict__ wr,
    const float* __restrict__ att_in, const float* __restrict__ dec,
    const float* __restrict__ c1w, const float* __restrict__ c1b,
    float* __restrict__ out_attsum,
    const float* __restrict__ wb, const float* __restrict__ g,
    const float* __restrict__ bb, const float* __restrict__ rm,
    const float* __restrict__ rv, float* __restrict__ cs, float* __restrict__ csh,
    const int* __restrict__ input_a, const float* __restrict__ input_hidden,
    const float* __restrict__ emb_w,
    const float* __restrict__ w_ih, const float* __restrict__ w_hh,
    const float* __restrict__ b_ih, const float* __restrict__ b_hh,
    float* __restrict__ gi, float* __restrict__ gh,
    float* __restrict__ e_zero,
    const int* __restrict__ h_mask, const int* __restrict__ w_mask,
    int* __restrict__ wl_cnt, int* __restrict__ wl_conv, int* __restrict__ wl_et)
{
    int blk = blockIdx.x, t = threadIdx.x;
    if (blk < 1024) {                       // ua_w fp32 -> bf16
        int idx = blk * 256 + t;
        ub[idx] = f2bf(ua_w[idx]);
    } else if (blk < 1280) {                // convtan_w -> w_r[tap][o][ci] bf16
        int idx = (blk - 1024) * 256 + t;   // 65536 = (o,ci)
        const float* p = cw + (size_t)idx * 9;
        #pragma unroll
        for (int k = 0; k < 9; ++k) wr[k * 65536 + idx] = f2bf(p[k]);
    } else if (blk < 1408) {                // att_sum = attention_sum + conv1(dec)
        int idx = (blk - 1280) * 256 + t;   // < 32768
        int b = idx >> 11, hw = idx & 2047;
        int h = hw >> 6, w = hw & 63;
        float s = c1b[0];
        #pragma unroll
        for (int dy = 0; dy < 3; ++dy) {
            int hh = h + dy - 1;
            if ((unsigned)hh < (unsigned)HH) {
                #pragma unroll
                for (int dx = 0; dx < 3; ++dx) {
                    int wi = w + dx - 1;
                    if ((unsigned)wi < (unsigned)WW)
                        s += dec[b * HWSZ + hh * WW + wi] * c1w[dy * 3 + dx];
                }
            }
        }
        out_attsum[idx] = att_in[idx] + s;
    } else if (blk == 1408) {               // BN coef fold
        int c = t;
        float s = g[c] * rsqrtf(rv[c] + 1e-5f);
        cs[c] = s;
        csh[c] = (wb[c] - rm[c]) * s + bb[c];
    } else if (blk < 2177) {                // GRU1 gi/gh split-K (768 blocks)
        int gid = (blk - 1409) * 256 + t;   // 196608 = 768j * 16b * 16l
        int o = gid >> 4, l = gid & 15;
        int j = o >> 4, b = o & 15;
        int ia = input_a[b];
        float si = dotk<4>(w_ih + (size_t)j * 256, emb_w + (size_t)ia * 256, l);
        float sh = dotk<4>(w_hh + (size_t)j * 256, input_hidden + b * 256, l);
        si = red16(si); sh = red16(sh);
        if (l == 0) {
            gi[j * 16 + b] = si + b_ih[j];
            gh[j * 16 + b] = sh + b_hh[j];
        }
    } else if (blk < 2305) {                // zero e accumulator (128 blocks)
        e_zero[(blk - 2177) * 256 + t] = 0.f;
    } else {                                // build compact worklists (1 block)
        __shared__ int s_hm[16], s_wm[16], s_oc[16], s_oe[16];
        if (t < 16) { s_hm[t] = h_mask[t]; s_wm[t] = w_mask[t]; }
        __syncthreads();
        if (t == 0) {
            int oc = 0, oe = 0;
            for (int b = 0; b < 16; ++b) {
                s_oc[b] = oc; oc += s_hm[b];
                int nr = min(s_hm[b] + 1, 32);
                int nw = 1 + (s_wm[b] >= 32 ? 1 : 0);
                s_oe[b] = oe; oe += nr * nw;
            }
            wl_cnt[0] = oc;
            wl_cnt[1] = oe;
        }
        __syncthreads();
        for (int idx = t; idx < 512; idx += 256) {        // conv items (b,h)
            int b = idx >> 5, h = idx & 31;
            if (h < s_hm[b]) wl_conv[s_oc[b] + h] = (b << 5) | h;
        }
        for (int idx = t; idx < 1024; idx += 256) {       // et items (b,bx)
            int b = idx >> 6, bx = idx & 63;
            int row = bx >> 1, wh = bx & 1;
            int nr = min(s_hm[b] + 1, 32);
            int nw = 1 + (s_wm[b] >= 32 ? 1 : 0);
            if (row < nr && wh < nw)
                wl_et[s_oe[b] + row * nw + wh] = (b << 6) | bx;
        }
    }
}

// ---------------- K1b: GRU1 gates + emb passthrough + fc1 -> addc (fused) -------
__global__ __launch_bounds__(256) void k_frontbc(
    const int* __restrict__ input_a, const float* __restrict__ emb_w,
    const float* __restrict__ input_hidden,
    const float* __restrict__ gi, const float* __restrict__ gh,
    const float* __restrict__ fc1_w, const float* __restrict__ fc1_b,
    const float* __restrict__ ua_b, const float* __restrict__ uf_b,
    float* __restrict__ st, float* __restrict__ embv, float* __restrict__ addc)
{
    __shared__ float st_s[256];
    int b = blockIdx.x, i = threadIdx.x;
    float r = sigm(gi[i * 16 + b] + gh[i * 16 + b]);
    float z = sigm(gi[(256 + i) * 16 + b] + gh[(256 + i) * 16 + b]);
    float n = tanhf(gi[(512 + i) * 16 + b] + r * gh[(512 + i) * 16 + b]);
    float h0 = input_hidden[b * 256 + i];
    float v = (1.f - z) * n + z * h0;
    st_s[i] = v;
    st[b * 256 + i] = v;
    embv[b * 256 + i] = emb_w[(size_t)input_a[b] * 256 + i];
    __syncthreads();
    int c = i;
    const float* w = fc1_w + (size_t)c * 256;
    float acc = 0.f;
    for (int k = 0; k < 256; ++k) acc += st_s[k] * w[k];
    addc[b * 256 + c] = acc + fc1_b[c] + ua_b[c] + uf_b[c];
}

// ---------------- K3: et-GEMM via MFMA, compacted grid (1024 blocks 1-D) --------
// out[c=256][hw=32/block] = ua[c][k=1024] @ enc[k][hw]; NHWC bf16 out.
__global__ __launch_bounds__(256) void k_et(
    const float* __restrict__ enc, const unsigned short* __restrict__ ua_bf,
    const float* __restrict__ addc, const float* __restrict__ uf_w,
    const float* __restrict__ attsum,
    const int* __restrict__ wl_cnt, const int* __restrict__ wl_et,
    unsigned short* __restrict__ et)
{
    __shared__ __align__(16) unsigned short As[256 * 64];
    __shared__ __align__(16) unsigned short Bs[32 * 64];
    int id = blockIdx.x;
    if (id >= wl_cnt[1]) return;            // compacted: active ids contiguous
    int ent = wl_et[id];
    int b = ent >> 6, bx = ent & 63;
    int hw0 = bx * 32;
    int t = threadIdx.x;
    int wv = t >> 6;
    int l15 = t & 15, quad = (t >> 4) & 3;
    int xb = l15 & 7;
    f32x4 acc[4][2];
    #pragma unroll
    for (int i = 0; i < 4; ++i)
        #pragma unroll
        for (int j = 0; j < 2; ++j) acc[i][j] = (f32x4)0.f;

    // B staging role: pixel p (0..31), k-octet g3 (0..7) within BK=64
    int p = t & 31, g3 = t >> 5;
    const float* encb = enc + (size_t)b * ENC * HWSZ + hw0 + p;

    float pfv[8];
    {   // prologue prefetch for k0 = 0
        const float* ep = encb + (size_t)(g3 * 8) * HWSZ;
        #pragma unroll
        for (int j = 0; j < 8; ++j) pfv[j] = ep[(size_t)j * HWSZ];
    }

    for (int k0 = 0; k0 < ENC; k0 += 64) {
        short8 bv;
        #pragma unroll
        for (int j = 0; j < 8; ++j) bv[j] = (short)f2bf(pfv[j]);
        if (k0 + 64 < ENC) {
            const float* ep = encb + (size_t)(k0 + 64 + g3 * 8) * HWSZ;
            #pragma unroll
            for (int j = 0; j < 8; ++j) pfv[j] = ep[(size_t)j * HWSZ];
        }
        __syncthreads();   // all waves done reading LDS from previous k-step

        // A-tile: 2048 slots (c=s>>3, kq=s&7); dest linear, source pre-swizzled
        #pragma unroll
        for (int i = 0; i < 8; ++i) {
            int s = t + 256 * i;
            int c = s >> 3, kq = s & 7;
            const unsigned short* src =
                ua_bf + (size_t)c * ENC + k0 + ((kq ^ (c & 7)) << 3);
#ifdef HAVE_GLD_LDS
            gld_lds16(src, As + (size_t)(wv * 64 + 256 * i) * 8);
#else
            *(uint4*)(As + (size_t)s * 8) = *(const uint4*)src;
#endif
        }
        // B-tile: swizzled ds_write_b128
        *(short8*)(Bs + p * 64 + ((g3 ^ (p & 7)) << 3)) = bv;
        __syncthreads();   // drains gld_lds (vmcnt) + ds_write (lgkm)

        #pragma unroll
        for (int kk = 0; kk < 2; ++kk) {
            short8 af[4], bfr[2];
            #pragma unroll
            for (int mt = 0; mt < 4; ++mt) {
                int c = wv * 64 + mt * 16 + l15;
                af[mt] = *(const short8*)(As + c * 64 + (((kk * 4 + quad) ^ xb) << 3));
            }
            #pragma unroll
            for (int nt = 0; nt < 2; ++nt) {
                int n = nt * 16 + l15;
                bfr[nt] = *(const short8*)(Bs + n * 64 + (((kk * 4 + quad) ^ xb) << 3));
            }
            #pragma unroll
            for (int mt = 0; mt < 4; ++mt)
                #pragma unroll
                for (int nt = 0; nt < 2; ++nt)
                    acc[mt][nt] = __builtin_amdgcn_mfma_f32_16x16x32_bf16(
                        af[mt], bfr[nt], acc[mt][nt], 0, 0, 0);
        }
    }
    // epilogue: + addc[c] + attsum[hw]*uf_w[c], store NHWC bf16
    float at[2];
    #pragma unroll
    for (int nt = 0; nt < 2; ++nt) at[nt] = attsum[b * HWSZ + hw0 + nt * 16 + l15];
    #pragma unroll
    for (int mt = 0; mt < 4; ++mt) {
        int cb = wv * 64 + mt * 16 + quad * 4;
        float ad[4], uw[4];
        #pragma unroll
        for (int r = 0; r < 4; ++r) { ad[r] = addc[b * 256 + cb + r]; uw[r] = uf_w[cb + r]; }
        #pragma unroll
        for (int nt = 0; nt < 2; ++nt) {
            ushort4 pk;
            pk.x = f2bf(acc[mt][nt][0] + ad[0] + at[nt] * uw[0]);
            pk.y = f2bf(acc[mt][nt][1] + ad[1] + at[nt] * uw[1]);
            pk.z = f2bf(acc[mt][nt][2] + ad[2] + at[nt] * uw[2]);
            pk.w = f2bf(acc[mt][nt][3] + ad[3] + at[nt] * uw[3]);
            *(ushort4*)(et + (size_t)(b * HWSZ + hw0 + nt * 16 + l15) * 256 + cb) = pk;
        }
    }
}

// ---------------- K4: conv3x3 implicit-GEMM MFMA + BN + tanh + v-dot ------------
// v9: R8's verified body + compacted 1-D grid. Active blocks occupy ids
// [0, 2*cnt): CUs fill with 4 ACTIVE blocks (restores v1's co-residency);
// the dead tail exits in bulk. Body identical to R8 (84.4us-family schedule,
// mask-capped nt/staging).
__global__ __launch_bounds__(256) void k_conv(
    const unsigned short* __restrict__ et, const unsigned short* __restrict__ wr,
    const float* __restrict__ cs, const float* __restrict__ csh,
    const float* __restrict__ v_w,
    const int* __restrict__ wl_cnt, const int* __restrict__ wl_conv,
    const int* __restrict__ w_mask,
    float* __restrict__ e_out)
{
    __shared__ unsigned short Ls[66 * 264];  // [pixel 0..65][ci 256 pad->264]
    __shared__ float red[64][17];
    int id = blockIdx.x;
    if (id >= 2 * wl_cnt[0]) return;         // compacted: active ids contiguous
    int ent = wl_conv[id >> 1];
    int b = ent >> 5, h = ent & 31;
    int c0 = (id & 1) * 128;
    int t = threadIdx.x;
    int wm = w_mask[b];
    int ntmax = (wm + 15) >> 4;              // 1..4: pixel groups with live output
    int pxmax = ntmax * 16 + 2;              // staged Ls rows needed (<= 66)
    int wv = t >> 6, l15 = t & 15, quad = (t >> 4) & 3;
    f32x4 acc[2][4];
    #pragma unroll
    for (int i = 0; i < 2; ++i)
        #pragma unroll
        for (int j = 0; j < 4; ++j) acc[i][j] = (f32x4)0.f;

    for (int dy = 0; dy < 3; ++dy) {
        int hr = h + dy - 1;
        if ((unsigned)hr >= (unsigned)HH) continue;   // block-uniform
        __syncthreads();
        const unsigned short* rowp = et + (size_t)(b * HH + hr) * WW * 256;
        for (int idx = t; idx < pxmax * 32; idx += 256) {  // pixels x 32 chunks
            int p = idx >> 5, s = idx & 31;
            short8 v;
            if (p == 0 || p == 65) v = (short8)0;
            else v = *(const short8*)(rowp + (p - 1) * 256 + s * 8);
            *(short8*)(Ls + p * 264 + s * 8) = v;
        }
        __syncthreads();
        for (int dx = 0; dx < 3; ++dx) {
            int tap = dy * 3 + dx;
            const unsigned short* wrt = wr + (size_t)tap * 65536;
            #pragma unroll
            for (int kc = 0; kc < 8; ++kc) {
                short8 af[2], bfr[4];
                #pragma unroll
                for (int mt = 0; mt < 2; ++mt)
                    af[mt] = *(const short8*)(wrt +
                        (size_t)(c0 + wv * 32 + mt * 16 + l15) * 256 + kc * 32 + quad * 8);
                #pragma unroll
                for (int nt = 0; nt < 4; ++nt) {
                    if (nt < ntmax) {
                        int wrow = nt * 16 + l15 + dx;     // 0..65, pads zero
                        bfr[nt] = *(const short8*)(Ls + wrow * 264 + kc * 32 + quad * 8);
                    }
                }
                #pragma unroll
                for (int mt = 0; mt < 2; ++mt)
                    #pragma unroll
                    for (int nt = 0; nt < 4; ++nt)
                        if (nt < ntmax)
                            acc[mt][nt] = __builtin_amdgcn_mfma_f32_16x16x32_bf16(
                                af[mt], bfr[nt], acc[mt][nt], 0, 0, 0);
            }
        }
    }
    // epilogue: y = acc*cs + csh; partial e = sum tanh(y)*v_w over this lane's c
    float p[4] = {0.f, 0.f, 0.f, 0.f};
    #pragma unroll
    for (int mt = 0; mt < 2; ++mt) {
        int cb = c0 + wv * 32 + mt * 16 + quad * 4;
        #pragma unroll
        for (int r = 0; r < 4; ++r) {
            float sc = cs[cb + r], sh = csh[cb + r], vw = v_w[cb + r];
            #pragma unroll
            for (int nt = 0; nt < 4; ++nt) {
                if (nt < ntmax) {
                    float x = acc[mt][nt][r] * sc + sh;
                    p[nt] += tanhf(x) * vw;
                }
            }
        }
    }
    __syncthreads();
    #pragma unroll
    for (int nt = 0; nt < 4; ++nt) red[nt * 16 + l15][wv * 4 + quad] = p[nt];
    __syncthreads();
    if (t < 64) {
        float s = 0.f;
        #pragma unroll
        for (int i = 0; i < 16; ++i) s += red[t][i];
        atomicAdd(&e_out[(b * HH + h) * WW + t], s);   // two c-halves accumulate
    }
}

// ---------------- K5+K6 fused: softmax(e)->alpha (LDS) + ct reduction -----------
__global__ __launch_bounds__(256) void k_ctalpha(
    const float* __restrict__ enc, const float* __restrict__ e_acc,
    const float* __restrict__ v_b,
    const int* __restrict__ h_mask, const int* __restrict__ w_mask,
    float* __restrict__ alpha_out, float* __restrict__ ct)
{
    __shared__ float a_s[HWSZ];
    __shared__ float rbuf[4];
    int b = blockIdx.y, cg = blockIdx.x, t = threadIdx.x;
    int hm = h_mask[b], wm = w_mask[b];
    float vb = v_b[0];
    float vals[8];
    float psum = 0.f;
    #pragma unroll
    for (int u = 0; u < 8; ++u) {
        int s = u * 256 + t;
        int h = s >> 6, w = s & 63;
        float e = e_acc[b * HWSZ + s] + vb;
        float ex = (h < hm && w < wm) ? expf(e) : 0.f;
        vals[u] = ex;
        psum += ex;
    }
    for (int off = 1; off < 64; off <<= 1) psum += __shfl_xor(psum, off, 64);
    if ((t & 63) == 0) rbuf[t >> 6] = psum;
    __syncthreads();
    float inv = 1.f / (rbuf[0] + rbuf[1] + rbuf[2] + rbuf[3] + 1e-8f);
    #pragma unroll
    for (int u = 0; u < 8; ++u) {
        int s = u * 256 + t;
        float a = vals[u] * inv;
        a_s[s] = a;
        if (cg == 0) alpha_out[b * HWSZ + s] = a;
    }
    __syncthreads();
    int wave = t >> 6, lane = t & 63;
    int c = cg * 4 + wave;
    const float* ep = enc + ((size_t)(b * ENC + c)) * HWSZ;
    float s = 0.f;
    int imax = hm * 64;                       // a_s == 0 beyond masked rows
    for (int i = lane; i < imax; i += 64) s += ep[i] * a_s[i];
    for (int off = 32; off; off >>= 1) s += __shfl_down(s, off, 64);
    if (lane == 0) ct[b * ENC + c] = s;
}

// ---------------- K7a: gi/gh for GRU2, split-K-16 (768 blocks) ------------------
__global__ __launch_bounds__(256) void k_gru2a(
    const float* __restrict__ ct, const float* __restrict__ st,
    const float* __restrict__ w_ih, const float* __restrict__ w_hh,
    const float* __restrict__ b_ih, const float* __restrict__ b_hh,
    float* __restrict__ gi, float* __restrict__ gh)
{
    int gid = blockIdx.x * 256 + threadIdx.x;
    int o = gid >> 4, l = gid & 15;
    int j = o >> 4, b = o & 15;
    float si = dotk<16>(w_ih + (size_t)j * ENC, ct + b * ENC, l);
    float sh = dotk<4>(w_hh + (size_t)j * 256, st + b * 256, l);
    si = red16(si); sh = red16(sh);
    if (l == 0) {
        gi[j * 16 + b] = si + b_ih[j];
        gh[j * 16 + b] = sh + b_hh[j];
    }
}

// ---------------- K7b: GRU2 gates -> h2 / hidden_next ---------------------------
__global__ __launch_bounds__(256) void k_gates2(
    const float* __restrict__ st, const float* __restrict__ gi,
    const float* __restrict__ gh, float* __restrict__ h2,
    float* __restrict__ out_hidden)
{
    int b = blockIdx.x, i = threadIdx.x;
    float r = sigm(gi[i * 16 + b] + gh[i * 16 + b]);
    float z = sigm(gi[(256 + i) * 16 + b] + gh[(256 + i) * 16 + b]);
    float n = tanhf(gi[(512 + i) * 16 + b] + r * gh[(512 + i) * 16 + b]);
    float v = (1.f - z) * n + z * st[b * 256 + i];
    h2[b * 256 + i] = v;
    out_hidden[b * 256 + i] = v;
}

// ---------------- K8: pre = h2@fc2^T + emb@emb2^T + ct@wc^T, split-K-16 ---------
__global__ __launch_bounds__(256) void k_pre(
    const float* __restrict__ h2, const float* __restrict__ emb,
    const float* __restrict__ ct,
    const float* __restrict__ fc2_w, const float* __restrict__ fc2_b,
    const float* __restrict__ emb2_w, const float* __restrict__ emb2_b,
    const float* __restrict__ wc_w, const float* __restrict__ wc_b,
    float* __restrict__ pre)
{
    int gid = blockIdx.x * 256 + threadIdx.x;  // 128 blocks: 128j*16b*16l
    int o = gid >> 4, l = gid & 15;
    int j = o >> 4, b = o & 15;
    float s = dotk<4>(fc2_w + (size_t)j * 256, h2 + b * 256, l)
            + dotk<4>(emb2_w + (size_t)j * 256, emb + b * 256, l)
            + dotk<16>(wc_w + (size_t)j * ENC, ct + b * ENC, l);
    s = red16(s);
    if (l == 0) pre[b * 128 + j] = s + fc2_b[j] + emb2_b[j] + wc_b[j];
}

// ---------------- K9: logits = pre @ out_w^T + out_b, split-K-16 ----------------
__global__ __launch_bounds__(256) void k_logits(
    const float* __restrict__ pre, const float* __restrict__ out_w,
    const float* __restrict__ out_b, float* __restrict__ logits)
{
    int gid = blockIdx.x * 256 + threadIdx.x;  // 5000 blocks: 5000j*16b*16l
    int o = gid >> 4, l = gid & 15;
    int j = o >> 4, b = o & 15;
    float s = dotk<2>(out_w + (size_t)j * 128, pre + b * 128, l);
    s = red16(s);
    if (l == 0) logits[b * VOCAB + j] = s + out_b[j];
}

// ---------------- K10: log_softmax ----------------------------------------------
__global__ __launch_bounds__(256) void k_lsm(
    const float* __restrict__ logits, float* __restrict__ out)
{
    __shared__ float buf[VOCAB];
    __shared__ float rbuf[4];
    int b = blockIdx.x, t = threadIdx.x;
    float mx = -1e30f;
    for (int s = t; s < VOCAB; s += 256) {
        float v = logits[b * VOCAB + s];
        buf[s] = v;
        mx = fmaxf(mx, v);
    }
    for (int off = 1; off < 64; off <<= 1) mx = fmaxf(mx, __shfl_xor(mx, off, 64));
    if ((t & 63) == 0) rbuf[t >> 6] = mx;
    __syncthreads();
    mx = fmaxf(fmaxf(rbuf[0], rbuf[1]), fmaxf(rbuf[2], rbuf[3]));
    __syncthreads();
    float se = 0.f;
    for (int s = t; s < VOCAB; s += 256) se += expf(buf[s] - mx);
    for (int off = 1; off < 64; off <<= 1) se += __shfl_xor(se, off, 64);
    if ((t & 63) == 0) rbuf[t >> 6] = se;
    __syncthreads();
    float lse = mx + logf(rbuf[0] + rbuf[1] + rbuf[2] + rbuf[3]);
    for (int s = t; s < VOCAB; s += 256) out[b * VOCAB + s] = buf[s] - lse;
}

extern "C" void kernel_launch(void* const* d_in, const int* in_sizes, int n_in,
                              void* d_out, int out_size, void* d_ws, size_t ws_size,
                              hipStream_t stream)
{
    const int*   input_a      = (const int*)d_in[0];
    const float* input_hidden = (const float*)d_in[1];
    const float* enc          = (const float*)d_in[2];
    const float* att_in       = (const float*)d_in[3];
    const float* dec_att      = (const float*)d_in[4];
    const int*   h_mask       = (const int*)d_in[5];
    const int*   w_mask       = (const int*)d_in[6];
    const float* emb_w        = (const float*)d_in[11];
    const float* g1_wih       = (const float*)d_in[12];
    const float* g1_whh       = (const float*)d_in[13];
    const float* g1_bih       = (const float*)d_in[14];
    const float* g1_bhh       = (const float*)d_in[15];
    const float* fc1_w        = (const float*)d_in[16];
    const float* fc1_b        = (const float*)d_in[17];
    const float* g2_wih       = (const float*)d_in[18];
    const float* g2_whh       = (const float*)d_in[19];
    const float* g2_bih       = (const float*)d_in[20];
    const float* g2_bhh       = (const float*)d_in[21];
    const float* out_w        = (const float*)d_in[22];
    const float* out_b        = (const float*)d_in[23];
    const float* emb2_w       = (const float*)d_in[24];
    const float* emb2_b       = (const float*)d_in[25];
    const float* c1w          = (const float*)d_in[26];
    const float* c1b          = (const float*)d_in[27];
    const float* ctw          = (const float*)d_in[28];
    const float* ctb          = (const float*)d_in[29];
    const float* fc2_w        = (const float*)d_in[30];
    const float* fc2_b        = (const float*)d_in[31];
    const float* ua_w         = (const float*)d_in[32];
    const float* ua_b         = (const float*)d_in[33];
    const float* uf_w         = (const float*)d_in[34];
    const float* uf_b         = (const float*)d_in[35];
    const float* v_w          = (const float*)d_in[36];
    const float* v_b          = (const float*)d_in[37];
    const float* wc_w         = (const float*)d_in[38];
    const float* wc_b         = (const float*)d_in[39];
    const float* bn_g         = (const float*)d_in[40];
    const float* bn_b         = (const float*)d_in[41];
    const float* bn_rm        = (const float*)d_in[42];
    const float* bn_rv        = (const float*)d_in[43];

    // output layout: log_softmax(16x5000) | hidden_next(16x256) | alpha(16x2048) | att_sum(16x2048)
    float* out        = (float*)d_out;
    float* out_logits = out;
    float* out_hidden = out + 80000;
    float* out_alpha  = out + 84096;
    float* out_attsum = out + 116864;

    // workspace layout
    char* ws = (char*)d_ws;
    unsigned short* et_t  = (unsigned short*)ws;                 // 16.78 MB (NHWC bf16)
    unsigned short* ua_bf = (unsigned short*)(ws + 16777216);    // 0.52 MB
    unsigned short* w_r   = (unsigned short*)(ws + 17301504);    // 1.18 MB
    float* f      = (float*)(ws + 18481152);
    float* st     = f;             // 4096
    float* embv   = f + 4096;      // 4096
    float* addc   = f + 8192;      // 4096
    float* e_ws   = f + 12288;     // 32768
    float* ct     = f + 45056;     // 16384
    float* h2     = f + 61440;     // 4096
    float* pre    = f + 65536;     // 2048
    float* logits = f + 67584;     // 80000
    float* gi1    = f + 147584;    // 12288
    float* gh1    = f + 159872;    // 12288
    float* gi2    = f + 172160;    // 12288
    float* gh2    = f + 184448;    // 12288
    float* cs     = f + 196736;    // 256
    float* csh    = f + 196992;    // 256
    int*   wl_cnt  = (int*)(f + 197248);   // 2 ints
    int*   wl_conv = wl_cnt + 2;           // 512 ints
    int*   wl_et   = wl_cnt + 514;         // 1024 ints

    k_prep<<<2306, 256, 0, stream>>>(ua_w, ua_bf, ctw, w_r,
                                     att_in, dec_att, c1w, c1b, out_attsum,
                                     ctb, bn_g, bn_b, bn_rm, bn_rv, cs, csh,
                                     input_a, input_hidden, emb_w,
                                     g1_wih, g1_whh, g1_bih, g1_bhh, gi1, gh1,
                                     e_ws, h_mask, w_mask,
                                     wl_cnt, wl_conv, wl_et);
    k_frontbc<<<16, 256, 0, stream>>>(input_a, emb_w, input_hidden, gi1, gh1,
                                      fc1_w, fc1_b, ua_b, uf_b, st, embv, addc);

    k_et<<<1024, 256, 0, stream>>>(enc, ua_bf, addc, uf_w, out_attsum,
                                   wl_cnt, wl_et, et_t);
    k_conv<<<1024, 256, 0, stream>>>(et_t, w_r, cs, csh, v_w,
                                     wl_cnt, wl_conv, w_mask, e_ws);

    k_ctalpha<<<dim3(256, 16), 256, 0, stream>>>(enc, e_ws, v_b, h_mask, w_mask,
                                                 out_alpha, ct);
    k_gru2a<<<768, 256, 0, stream>>>(ct, st, g2_wih, g2_whh, g2_bih, g2_bhh, gi2, gh2);
    k_gates2<<<16, 256, 0, stream>>>(st, gi2, gh2, h2, out_hidden);
    k_pre<<<128, 256, 0, stream>>>(h2, embv, ct, fc2_w, fc2_b, emb2_w, emb2_b,
                                   wc_w, wc_b, pre);
    k_logits<<<5000, 256, 0, stream>>>(pre, out_w, out_b, logits);
    k_lsm<<<16, 256, 0, stream>>>(logits, out_logits);
}